// Round 4
// baseline (1594.302 us; speedup 1.0000x reference)
//
#include <hip/hip_runtime.h>

typedef unsigned short u16;
typedef unsigned int u32;
typedef __attribute__((ext_vector_type(8))) short bf16x8;
typedef __attribute__((ext_vector_type(4))) float f32x4;

// B=64 T=20 D_IN=512 H=512 D_ENC=2048 P=196 D_ATT=512
#define NB 64
#define NT 20
#define NH 512
#define NP 196
#define NE 2048
#define NA 512

__device__ __forceinline__ u16 f2bf(float f) {
  u32 b = __float_as_uint(f);
  return (u16)((b + 0x7FFFu + ((b >> 16) & 1u)) >> 16);
}
__device__ __forceinline__ float bf2f(u16 u) { return __uint_as_float(((u32)u) << 16); }
__device__ __forceinline__ float tanh_fast(float x) {
  float xc = fminf(fmaxf(x, -15.f), 15.f);
  float e2 = __builtin_amdgcn_exp2f(xc * 2.885390082f);
  return (e2 - 1.f) * __builtin_amdgcn_rcpf(e2 + 1.f);
}
__device__ __forceinline__ float sigmoid_fast(float x) {
  return __builtin_amdgcn_rcpf(1.f + __builtin_amdgcn_exp2f(x * -1.44269504f));
}

// ---------------- f32 -> bf16 convert (vectorized, grid-stride) ----------------
__global__ __launch_bounds__(256) void conv_bf16(const float4* __restrict__ src,
                                                 u16* __restrict__ dst, int n4) {
  int i = blockIdx.x * 256 + threadIdx.x;
  int stride = gridDim.x * 256;
  for (; i < n4; i += stride) {
    float4 v = src[i];
    u32 lo = (u32)f2bf(v.x) | ((u32)f2bf(v.y) << 16);
    u32 hi = (u32)f2bf(v.z) | ((u32)f2bf(v.w) << 16);
    *(uint2*)(dst + (size_t)i * 4) = make_uint2(lo, hi);
  }
}

// ---------------- x [b][t][512] f32 -> xbT [t][b][512] bf16 ----------------
__global__ __launch_bounds__(128) void conv_x(const float* __restrict__ x,
                                              u16* __restrict__ xbT) {
  int b = blockIdx.x, t = blockIdx.y, tid = threadIdx.x;
  float4 v = *(const float4*)(x + ((size_t)b * NT + t) * 512 + tid * 4);
  u32 lo = (u32)f2bf(v.x) | ((u32)f2bf(v.y) << 16);
  u32 hi = (u32)f2bf(v.z) | ((u32)f2bf(v.w) << 16);
  *(uint2*)(xbT + ((size_t)t * NB + b) * 512 + tid * 4) = make_uint2(lo, hi);
}

// ------------- transpose f32 [K][512] (+row offset) -> bf16 [z*512+n][K] -------------
__global__ __launch_bounds__(256) void transpose_w(const float* __restrict__ W0,
                                                   const float* __restrict__ W1,
                                                   const float* __restrict__ W2,
                                                   const float* __restrict__ W3,
                                                   u16* __restrict__ dst, int row_off, int K) {
  const float* src = blockIdx.z == 0 ? W0 : blockIdx.z == 1 ? W1 : blockIdx.z == 2 ? W2 : W3;
  __shared__ float tile[32][33];
  int k0 = blockIdx.x * 32, n0 = blockIdx.y * 32;
  int tx = threadIdx.x & 31, ty = threadIdx.x >> 5;  // 32 x 8
#pragma unroll
  for (int i = 0; i < 4; ++i)
    tile[ty + i * 8][tx] = src[(size_t)(row_off + k0 + ty + i * 8) * 512 + n0 + tx];
  __syncthreads();
#pragma unroll
  for (int i = 0; i < 4; ++i) {
    int n = n0 + ty + i * 8, k = k0 + tx;
    dst[((size_t)blockIdx.z * 512 + n) * K + k] = f2bf(tile[tx][ty + i * 8]);
  }
}

// ---------------- generic bf16 MFMA GEMM: C[M][N] = A[M][K] * BT[N][K]^T (+bias) ----------------
template <bool OUT_BF16, bool BIAS>
__global__ __launch_bounds__(256) void gemm_bf16(const u16* __restrict__ A,
                                                 const u16* __restrict__ BT,
                                                 const float* __restrict__ bias,
                                                 void* __restrict__ Cout, int M, int N, int K) {
  __shared__ u16 lA[128 * 64];
  __shared__ u16 lB[128 * 64];
  const int tid = threadIdx.x;
  const int lane = tid & 63;
  const int wid = tid >> 6;
  const int m0 = blockIdx.x * 128, n0 = blockIdx.y * 128;
  const int wm = (wid >> 1) * 64, wn = (wid & 1) * 64;
  f32x4 acc[4][4] = {};

  for (int k0 = 0; k0 < K; k0 += 64) {
    __syncthreads();
#pragma unroll
    for (int it = 0; it < 4; ++it) {
      int c = tid + it * 256;
      int r = c >> 3, c7 = c & 7;
      uint4 va = *(const uint4*)(A + (size_t)(m0 + r) * K + k0 + c7 * 8);
      uint4 vb = *(const uint4*)(BT + (size_t)(n0 + r) * K + k0 + c7 * 8);
      int ldsoff = r * 64 + ((c7 ^ (r & 7)) * 8);
      *(uint4*)(lA + ldsoff) = va;
      *(uint4*)(lB + ldsoff) = vb;
    }
    __syncthreads();
#pragma unroll
    for (int kk = 0; kk < 2; ++kk) {
      int kchunk = kk * 4 + (lane >> 4);
      bf16x8 af[4], bg[4];
#pragma unroll
      for (int i = 0; i < 4; ++i) {
        int row = wm + i * 16 + (lane & 15);
        af[i] = *(const bf16x8*)(lA + row * 64 + ((kchunk ^ (row & 7)) * 8));
        int rowb = wn + i * 16 + (lane & 15);
        bg[i] = *(const bf16x8*)(lB + rowb * 64 + ((kchunk ^ (rowb & 7)) * 8));
      }
#pragma unroll
      for (int i = 0; i < 4; ++i)
#pragma unroll
        for (int j = 0; j < 4; ++j)
          acc[i][j] = __builtin_amdgcn_mfma_f32_16x16x32_bf16(af[i], bg[j], acc[i][j], 0, 0, 0);
    }
  }
#pragma unroll
  for (int i = 0; i < 4; ++i) {
    int m = m0 + wm + i * 16 + ((lane >> 4) * 4);
#pragma unroll
    for (int j = 0; j < 4; ++j) {
      int n = n0 + wn + j * 16 + (lane & 15);
      float bv = BIAS ? bias[n] : 0.f;
#pragma unroll
      for (int r = 0; r < 4; ++r) {
        float val = acc[i][j][r] + bv;
        if (OUT_BF16)
          ((u16*)Cout)[(size_t)(m + r) * N + n] = f2bf(val);
        else
          ((float*)Cout)[(size_t)(m + r) * N + n] = val;
      }
    }
  }
}

// ============ fused attention: e + softmax + ctx, one block per (b, col-half) ============
// grid 128 = b*2 + ch, 1024 threads (16 waves).
__global__ __launch_bounds__(1024) void attn_ctx(const u16* __restrict__ fpb,
                                                 const float* __restrict__ hwap,
                                                 const float* __restrict__ v,
                                                 const u16* __restrict__ cnnb,
                                                 u16* __restrict__ ctxb, int t) {
  const int b = blockIdx.x >> 1;
  const int ch = blockIdx.x & 1;  // which 1024 cols of ctx
  const int tid = threadIdx.x;
  const int lane = tid & 63, wid = tid >> 6;
  __shared__ float hwa[512];
  __shared__ float vv[512];
  __shared__ float sm[256];
  __shared__ float alp[200];
  __shared__ float red[8192];  // ctx partials [pg8][cu128][8]; red[0..255] doubles as e[]

  // hwa[a] = sum_nt hwap[nt][b][a]   (h==0 at t==0)
  if (tid < 512) {
    float s = 0.f;
    if (t > 0) {
#pragma unroll 8
      for (int nt = 0; nt < 32; ++nt) s += hwap[((size_t)nt * 64 + b) * 512 + tid];
    }
    hwa[tid] = s;
    vv[tid] = v[tid];
  }
  if (tid >= 196 && tid < 256) red[tid] = -3e38f;  // pad e[]
  __syncthreads();

  // e[p] = sum_a tanh(fp + hwa) * v   (one p per wave per iter)
  float hw[8], vr[8];
#pragma unroll
  for (int j = 0; j < 8; ++j) {
    hw[j] = hwa[lane * 8 + j];
    vr[j] = vv[lane * 8 + j];
  }
  for (int p = wid; p < NP; p += 16) {
    const u16* fp = fpb + ((size_t)b * NP + p) * 512 + lane * 8;
    uint4 raw = *(const uint4*)fp;
    u32 w[4] = {raw.x, raw.y, raw.z, raw.w};
    float part = 0.f;
#pragma unroll
    for (int j = 0; j < 8; ++j) {
      u16 u = (u16)(w[j >> 1] >> ((j & 1) * 16));
      part += tanh_fast(bf2f(u) + hw[j]) * vr[j];
    }
#pragma unroll
    for (int off = 32; off > 0; off >>= 1) part += __shfl_xor(part, off);
    if (lane == 0) red[p] = part;
  }
  __syncthreads();

  // softmax over 196 (threads <256 active in reductions; all hit barriers)
  float ev = (tid < 256) ? red[tid] : -3e38f;
  if (tid < 256) sm[tid] = ev;
  __syncthreads();
  for (int s = 128; s > 0; s >>= 1) {
    if (tid < s) sm[tid] = fmaxf(sm[tid], sm[tid + s]);
    __syncthreads();
  }
  float mx = sm[0];
  __syncthreads();
  float w = (tid < NP) ? __builtin_amdgcn_exp2f((ev - mx) * 1.44269504f) : 0.f;
  if (tid < 256) sm[tid] = w;
  __syncthreads();
  for (int s = 128; s > 0; s >>= 1) {
    if (tid < s) sm[tid] += sm[tid + s];
    __syncthreads();
  }
  float inv = __builtin_amdgcn_rcpf(sm[0]);
  if (tid < NP) alp[tid] = w * inv;
  __syncthreads();

  // ctx: 8 p-groups x 128 col-units of 8 (uint4 loads), LDS-reduce over p-groups
  {
    const int pg = tid >> 7, cu = tid & 127;
    const int col = ch * 1024 + cu * 8;
    const u16* base = cnnb + (size_t)b * NP * NE + col;
    float acc[8] = {};
    for (int i = 0; i < 25; ++i) {
      int p = pg + i * 8;
      if (p < NP) {
        float al = alp[p];
        uint4 raw = *(const uint4*)(base + (size_t)p * NE);
        u32 wds[4] = {raw.x, raw.y, raw.z, raw.w};
#pragma unroll
        for (int j = 0; j < 8; ++j)
          acc[j] += al * bf2f((u16)(wds[j >> 1] >> ((j & 1) * 16)));
      }
    }
#pragma unroll
    for (int j = 0; j < 8; ++j) red[tid * 8 + j] = acc[j];
    __syncthreads();
    if (tid < 512) {
      const int cu2 = tid >> 2, jp = tid & 3;
      float s0 = 0.f, s1 = 0.f;
#pragma unroll
      for (int g = 0; g < 8; ++g) {
        s0 += red[g * 1024 + cu2 * 8 + jp * 2];
        s1 += red[g * 1024 + cu2 * 8 + jp * 2 + 1];
      }
      u32 packed = (u32)f2bf(s0) | ((u32)f2bf(s1) << 16);
      *(u32*)(ctxb + (size_t)b * NE + ch * 1024 + cu2 * 8 + jp * 2) = packed;
    }
  }
}

// ------- gates GEMM (M=64,N=2048,K=2560) + LSTM cell + hWa partials, whct read ONCE -------
// grid 32 = nt (16-col tile of H), 1024 thr = 16 waves = 4 gates x 4 K-quarters (640 each).
// Each wave computes [64 x 16] for its (g, kh): 4 A-frags x 1 B-frag x 20 k-steps.
__global__ __launch_bounds__(1024) void gates_kernel(
    const u16* __restrict__ hprev, const u16* __restrict__ ctxb, const u16* __restrict__ whct,
    const float* __restrict__ xw, const float* __restrict__ bi, const float* __restrict__ bfg,
    const float* __restrict__ bc, const float* __restrict__ bo, float* __restrict__ cbuf,
    float* __restrict__ out, const float* __restrict__ wah, float* __restrict__ hwap,
    u16* __restrict__ hnext, int t) {
  const int nt = blockIdx.x;  // 0..31
  const int tid = threadIdx.x, lane = tid & 63, wid = tid >> 6;
  const int g = wid & 3, kh = wid >> 2;  // gate, K-quarter
  const int l15 = lane & 15;
  const u16* Bp = whct + (size_t)(g * 512 + nt * 16 + l15) * 2560;
  const int klo = kh * 640 + ((lane >> 4) * 8);
  const u16* hA[4];
  const u16* cAx[4];
#pragma unroll
  for (int i = 0; i < 4; ++i) {
    int row = i * 16 + l15;
    hA[i] = hprev + (size_t)row * 512;
    cAx[i] = ctxb + (size_t)row * 2048 - 512;  // valid for k >= 512
  }
  f32x4 acc[4] = {};
  if (kh == 0) {
    if (t > 0) {  // h == 0 at t == 0
#pragma unroll 4
      for (int ks = 0; ks < 16; ++ks) {
        int k = klo + ks * 32;
        bf16x8 bb = *(const bf16x8*)(Bp + k);
#pragma unroll
        for (int i = 0; i < 4; ++i) {
          bf16x8 a = *(const bf16x8*)(hA[i] + k);
          acc[i] = __builtin_amdgcn_mfma_f32_16x16x32_bf16(a, bb, acc[i], 0, 0, 0);
        }
      }
    }
#pragma unroll 4
    for (int ks = 16; ks < 20; ++ks) {
      int k = klo + ks * 32;
      bf16x8 bb = *(const bf16x8*)(Bp + k);
#pragma unroll
      for (int i = 0; i < 4; ++i) {
        bf16x8 a = *(const bf16x8*)(cAx[i] + k);
        acc[i] = __builtin_amdgcn_mfma_f32_16x16x32_bf16(a, bb, acc[i], 0, 0, 0);
      }
    }
  } else {
#pragma unroll 4
    for (int ks = 0; ks < 20; ++ks) {
      int k = klo + ks * 32;
      bf16x8 bb = *(const bf16x8*)(Bp + k);
#pragma unroll
      for (int i = 0; i < 4; ++i) {
        bf16x8 a = *(const bf16x8*)(cAx[i] + k);
        acc[i] = __builtin_amdgcn_mfma_f32_16x16x32_bf16(a, bb, acc[i], 0, 0, 0);
      }
    }
  }

  __shared__ float pre[16][64][16];  // [wid][b][n]  64 KB
  __shared__ float hlds[64][16];
  {
    const int rbase = (lane >> 4) * 4;
#pragma unroll
    for (int i = 0; i < 4; ++i)
#pragma unroll
      for (int r = 0; r < 4; ++r) pre[wid][i * 16 + rbase + r][l15] = acc[i][r];
  }
  __syncthreads();

  // cell update: 1024 threads = one (b,n) each
  {
    const int bb = tid >> 4, n = tid & 15;
    const int ng = nt * 16 + n;
    float P0 = pre[0][bb][n] + pre[4][bb][n] + pre[8][bb][n] + pre[12][bb][n];
    float P1 = pre[1][bb][n] + pre[5][bb][n] + pre[9][bb][n] + pre[13][bb][n];
    float P2 = pre[2][bb][n] + pre[6][bb][n] + pre[10][bb][n] + pre[14][bb][n];
    float P3 = pre[3][bb][n] + pre[7][bb][n] + pre[11][bb][n] + pre[15][bb][n];
    size_t xwo = ((size_t)t * NB + bb) * 2048 + ng;
    float ip = P0 + xw[xwo] + bi[ng];
    float fp = P1 + xw[xwo + 512] + bfg[ng];
    float cp = P2 + xw[xwo + 1024] + bc[ng];
    float op = P3 + xw[xwo + 1536] + bo[ng];
    float it = sigmoid_fast(ip), ft = sigmoid_fast(fp), ot = sigmoid_fast(op);
    float ctl = tanh_fast(cp);
    float cold = (t > 0) ? cbuf[(size_t)bb * 512 + ng] : 0.f;
    float cn = ft * cold + it * ctl;
    float hn = ot * tanh_fast(cn);
    cbuf[(size_t)bb * 512 + ng] = cn;
    hnext[(size_t)bb * 512 + ng] = f2bf(hn);
    out[((size_t)bb * NT + t) * 512 + ng] = hn;
    if (t == NT - 1) {
      out[(size_t)NB * NT * 512 + (size_t)bb * 512 + ng] = hn;
      out[(size_t)NB * NT * 512 + (size_t)NB * 512 + (size_t)bb * 512 + ng] = cn;
    }
    hlds[bb][n] = hn;
  }
  __syncthreads();

  // hWa partial: hwap[nt][b][a] = sum_{j<16} h[b][nt*16+j] * Wa_h[nt*16+j][a]
  {
    const int bh = tid >> 9, a = tid & 511;  // 2 b-halves x 512 a
    float wa[16];
#pragma unroll
    for (int j = 0; j < 16; ++j) wa[j] = wah[(size_t)(nt * 16 + j) * 512 + a];
    for (int bl = bh * 32; bl < bh * 32 + 32; ++bl) {
      float s = 0.f;
#pragma unroll
      for (int j = 0; j < 16; ++j) s += hlds[bl][j] * wa[j];
      hwap[((size_t)nt * 64 + bl) * 512 + a] = s;
    }
  }
}

// ======================= host launcher =======================
extern "C" void kernel_launch(void* const* d_in, const int* in_sizes, int n_in, void* d_out,
                              int out_size, void* d_ws, size_t ws_size, hipStream_t stream) {
  const float* x = (const float*)d_in[0];
  const float* cnn = (const float*)d_in[1];
  const float* Wi = (const float*)d_in[2];
  const float* bi = (const float*)d_in[3];
  const float* Wf = (const float*)d_in[4];
  const float* bfv = (const float*)d_in[5];
  const float* Wc = (const float*)d_in[6];
  const float* bc = (const float*)d_in[7];
  const float* Wo = (const float*)d_in[8];
  const float* bo = (const float*)d_in[9];
  const float* Waf = (const float*)d_in[10];
  const float* Wah = (const float*)d_in[11];
  const float* ba = (const float*)d_in[12];
  const float* v = (const float*)d_in[13];
  float* out = (float*)d_out;

  char* base = (char*)d_ws;
  size_t off = 0;
  auto alloc = [&](size_t bytes) {
    char* r = base + off;
    off += (bytes + 255) & ~(size_t)255;
    return r;
  };
  u16* cnnb = (u16*)alloc((size_t)NB * NP * NE * 2);       // 51.4 MB
  u16* fpb = (u16*)alloc((size_t)NB * NP * NA * 2);        // 12.8 MB
  u16* whct = (u16*)alloc((size_t)4 * 512 * 2560 * 2);     // 10.5 MB
  u16* wxt = (u16*)alloc((size_t)4 * 512 * 512 * 2);       // 2 MB
  u16* waft = (u16*)alloc((size_t)512 * 2048 * 2);         // 2 MB
  u16* xbT = (u16*)alloc((size_t)NT * NB * 512 * 2);       // 1.3 MB  [t][b][512]
  float* xw = (float*)alloc((size_t)NT * NB * 2048 * 4);   // 10.5 MB [t][b][2048]
  u16* hbuf = (u16*)alloc((size_t)2 * NB * 512 * 2);       // 128 KB (double buffer)
  float* cbuf = (float*)alloc((size_t)NB * 512 * 4);       // 128 KB
  u16* ctxb = (u16*)alloc((size_t)NB * 2048 * 2);          // 256 KB
  float* hwap = (float*)alloc((size_t)32 * NB * 512 * 4);  // 4 MB

  (void)ws_size;
  (void)in_sizes;
  (void)n_in;
  (void)out_size;

  // conversions / transposes
  conv_bf16<<<2048, 256, 0, stream>>>((const float4*)cnn, cnnb, (NB * NP * NE) / 4);
  conv_x<<<dim3(NB, NT), 128, 0, stream>>>(x, xbT);
  {
    dim3 g1(2560 / 32, 16, 4);
    transpose_w<<<g1, 256, 0, stream>>>(Wi, Wf, Wc, Wo, whct, 512, 2560);
    dim3 g2(512 / 32, 16, 4);
    transpose_w<<<g2, 256, 0, stream>>>(Wi, Wf, Wc, Wo, wxt, 0, 512);
    dim3 g3(2048 / 32, 16, 1);
    transpose_w<<<g3, 256, 0, stream>>>(Waf, Waf, Waf, Waf, waft, 0, 2048);
  }

  // feat_proj = cnn @ Wa_feat + ba  -> bf16 [12544][512]
  {
    dim3 g(12544 / 128, 512 / 128);
    gemm_bf16<true, true><<<g, 256, 0, stream>>>(cnnb, waft, ba, fpb, 12544, 512, 2048);
  }
  // xw = xT @ W[:512,:] (4 gates) -> f32 [t*64+b][2048]
  {
    dim3 g(1280 / 128, 2048 / 128);
    gemm_bf16<false, false><<<g, 256, 0, stream>>>(xbT, wxt, nullptr, xw, 1280, 2048, 512);
  }

  // 20-step recurrence: 2 kernels per step
  for (int t = 0; t < NT; ++t) {
    const u16* hprev = hbuf + (size_t)(t & 1) * NB * 512;
    u16* hnext = hbuf + (size_t)((t + 1) & 1) * NB * 512;
    attn_ctx<<<128, 1024, 0, stream>>>(fpb, hwap, v, cnnb, ctxb, t);
    gates_kernel<<<32, 1024, 0, stream>>>(hprev, ctxb, whct, xw, bi, bfv, bc, bo, cbuf, out, Wah,
                                          hwap, hnext, t);
  }
}

// Round 5
// 969.151 us; speedup vs baseline: 1.6451x; 1.6451x over previous
//
#include <hip/hip_runtime.h>

typedef unsigned short u16;
typedef unsigned int u32;
typedef __attribute__((ext_vector_type(8))) short bf16x8;
typedef __attribute__((ext_vector_type(4))) float f32x4;

// B=64 T=20 D_IN=512 H=512 D_ENC=2048 P=196 D_ATT=512
#define NB 64
#define NT 20
#define NH 512
#define NP 196
#define NE 2048
#define NA 512

__device__ __forceinline__ u16 f2bf(float f) {
  u32 b = __float_as_uint(f);
  return (u16)((b + 0x7FFFu + ((b >> 16) & 1u)) >> 16);
}
__device__ __forceinline__ float bf2f(u16 u) { return __uint_as_float(((u32)u) << 16); }
__device__ __forceinline__ float tanh_fast(float x) {
  float xc = fminf(fmaxf(x, -15.f), 15.f);
  float e2 = __builtin_amdgcn_exp2f(xc * 2.885390082f);
  return (e2 - 1.f) * __builtin_amdgcn_rcpf(e2 + 1.f);
}
__device__ __forceinline__ float sigmoid_fast(float x) {
  return __builtin_amdgcn_rcpf(1.f + __builtin_amdgcn_exp2f(x * -1.44269504f));
}

// ---------------- f32 -> bf16 convert (vectorized, grid-stride) ----------------
__global__ __launch_bounds__(256) void conv_bf16(const float4* __restrict__ src,
                                                 u16* __restrict__ dst, int n4) {
  int i = blockIdx.x * 256 + threadIdx.x;
  int stride = gridDim.x * 256;
  for (; i < n4; i += stride) {
    float4 v = src[i];
    u32 lo = (u32)f2bf(v.x) | ((u32)f2bf(v.y) << 16);
    u32 hi = (u32)f2bf(v.z) | ((u32)f2bf(v.w) << 16);
    *(uint2*)(dst + (size_t)i * 4) = make_uint2(lo, hi);
  }
}

// ---------------- x [b][t][512] f32 -> xbT [t][b][512] bf16 ----------------
__global__ __launch_bounds__(128) void conv_x(const float* __restrict__ x,
                                              u16* __restrict__ xbT) {
  int b = blockIdx.x, t = blockIdx.y, tid = threadIdx.x;
  float4 v = *(const float4*)(x + ((size_t)b * NT + t) * 512 + tid * 4);
  u32 lo = (u32)f2bf(v.x) | ((u32)f2bf(v.y) << 16);
  u32 hi = (u32)f2bf(v.z) | ((u32)f2bf(v.w) << 16);
  *(uint2*)(xbT + ((size_t)t * NB + b) * 512 + tid * 4) = make_uint2(lo, hi);
}

// ------------- transpose f32 [K][512] (+row offset) -> bf16 [z*512+n][K] -------------
__global__ __launch_bounds__(256) void transpose_w(const float* __restrict__ W0,
                                                   const float* __restrict__ W1,
                                                   const float* __restrict__ W2,
                                                   const float* __restrict__ W3,
                                                   u16* __restrict__ dst, int row_off, int K) {
  const float* src = blockIdx.z == 0 ? W0 : blockIdx.z == 1 ? W1 : blockIdx.z == 2 ? W2 : W3;
  __shared__ float tile[32][33];
  int k0 = blockIdx.x * 32, n0 = blockIdx.y * 32;
  int tx = threadIdx.x & 31, ty = threadIdx.x >> 5;  // 32 x 8
#pragma unroll
  for (int i = 0; i < 4; ++i)
    tile[ty + i * 8][tx] = src[(size_t)(row_off + k0 + ty + i * 8) * 512 + n0 + tx];
  __syncthreads();
#pragma unroll
  for (int i = 0; i < 4; ++i) {
    int n = n0 + ty + i * 8, k = k0 + tx;
    dst[((size_t)blockIdx.z * 512 + n) * K + k] = f2bf(tile[tx][ty + i * 8]);
  }
}

// ---------------- generic bf16 MFMA GEMM: C[M][N] = A[M][K] * BT[N][K]^T (+bias) ----------------
template <bool OUT_BF16, bool BIAS>
__global__ __launch_bounds__(256) void gemm_bf16(const u16* __restrict__ A,
                                                 const u16* __restrict__ BT,
                                                 const float* __restrict__ bias,
                                                 void* __restrict__ Cout, int M, int N, int K) {
  __shared__ u16 lA[128 * 64];
  __shared__ u16 lB[128 * 64];
  const int tid = threadIdx.x;
  const int lane = tid & 63;
  const int wid = tid >> 6;
  const int m0 = blockIdx.x * 128, n0 = blockIdx.y * 128;
  const int wm = (wid >> 1) * 64, wn = (wid & 1) * 64;
  f32x4 acc[4][4] = {};

  for (int k0 = 0; k0 < K; k0 += 64) {
    __syncthreads();
#pragma unroll
    for (int it = 0; it < 4; ++it) {
      int c = tid + it * 256;
      int r = c >> 3, c7 = c & 7;
      uint4 va = *(const uint4*)(A + (size_t)(m0 + r) * K + k0 + c7 * 8);
      uint4 vb = *(const uint4*)(BT + (size_t)(n0 + r) * K + k0 + c7 * 8);
      int ldsoff = r * 64 + ((c7 ^ (r & 7)) * 8);
      *(uint4*)(lA + ldsoff) = va;
      *(uint4*)(lB + ldsoff) = vb;
    }
    __syncthreads();
#pragma unroll
    for (int kk = 0; kk < 2; ++kk) {
      int kchunk = kk * 4 + (lane >> 4);
      bf16x8 af[4], bg[4];
#pragma unroll
      for (int i = 0; i < 4; ++i) {
        int row = wm + i * 16 + (lane & 15);
        af[i] = *(const bf16x8*)(lA + row * 64 + ((kchunk ^ (row & 7)) * 8));
        int rowb = wn + i * 16 + (lane & 15);
        bg[i] = *(const bf16x8*)(lB + rowb * 64 + ((kchunk ^ (rowb & 7)) * 8));
      }
#pragma unroll
      for (int i = 0; i < 4; ++i)
#pragma unroll
        for (int j = 0; j < 4; ++j)
          acc[i][j] = __builtin_amdgcn_mfma_f32_16x16x32_bf16(af[i], bg[j], acc[i][j], 0, 0, 0);
    }
  }
#pragma unroll
  for (int i = 0; i < 4; ++i) {
    int m = m0 + wm + i * 16 + ((lane >> 4) * 4);
#pragma unroll
    for (int j = 0; j < 4; ++j) {
      int n = n0 + wn + j * 16 + (lane & 15);
      float bv = BIAS ? bias[n] : 0.f;
#pragma unroll
      for (int r = 0; r < 4; ++r) {
        float val = acc[i][j][r] + bv;
        if (OUT_BF16)
          ((u16*)Cout)[(size_t)(m + r) * N + n] = f2bf(val);
        else
          ((float*)Cout)[(size_t)(m + r) * N + n] = val;
      }
    }
  }
}

// ============ fused attention: e + softmax + ctx, one block per (b, col-half) ============
// grid 128: b = blk & 63, ch = blk >> 6  (the 2 ch-blocks of one b share an XCD L2 for fpb).
__global__ __launch_bounds__(1024) void attn_ctx(const u16* __restrict__ fpb,
                                                 const u16* __restrict__ hwap,
                                                 const float* __restrict__ v,
                                                 const u16* __restrict__ cnnb,
                                                 u16* __restrict__ ctxb, int t) {
  const int b = blockIdx.x & 63;
  const int ch = blockIdx.x >> 6;  // which 1024 cols of ctx
  const int tid = threadIdx.x;
  const int lane = tid & 63, wid = tid >> 6;
  __shared__ float hwa[512];
  __shared__ float vv[512];
  __shared__ float sm[256];
  __shared__ float alp[200];
  __shared__ float red[8192];  // ctx partials [pg8][cu128][8]; red[0..255] doubles as e[]

  // hwa[a] = sum_nt hwap[nt][b][a]   (h==0 at t==0)
  if (tid < 512) {
    float s = 0.f;
    if (t > 0) {
#pragma unroll 8
      for (int nt = 0; nt < 32; ++nt) s += bf2f(hwap[((size_t)nt * 64 + b) * 512 + tid]);
    }
    hwa[tid] = s;
    vv[tid] = v[tid];
  }
  if (tid >= 196 && tid < 256) red[tid] = -3e38f;  // pad e[]
  __syncthreads();

  // e[p] = sum_a tanh(fp + hwa) * v   (one p per wave per iter)
  float hw[8], vr[8];
#pragma unroll
  for (int j = 0; j < 8; ++j) {
    hw[j] = hwa[lane * 8 + j];
    vr[j] = vv[lane * 8 + j];
  }
  for (int p = wid; p < NP; p += 16) {
    const u16* fp = fpb + ((size_t)b * NP + p) * 512 + lane * 8;
    uint4 raw = *(const uint4*)fp;
    u32 w[4] = {raw.x, raw.y, raw.z, raw.w};
    float part = 0.f;
#pragma unroll
    for (int j = 0; j < 8; ++j) {
      u16 u = (u16)(w[j >> 1] >> ((j & 1) * 16));
      part += tanh_fast(bf2f(u) + hw[j]) * vr[j];
    }
#pragma unroll
    for (int off = 32; off > 0; off >>= 1) part += __shfl_xor(part, off);
    if (lane == 0) red[p] = part;
  }
  __syncthreads();

  // softmax over 196 (threads <256 active in reductions; all hit barriers)
  float ev = (tid < 256) ? red[tid] : -3e38f;
  if (tid < 256) sm[tid] = ev;
  __syncthreads();
  for (int s = 128; s > 0; s >>= 1) {
    if (tid < s) sm[tid] = fmaxf(sm[tid], sm[tid + s]);
    __syncthreads();
  }
  float mx = sm[0];
  __syncthreads();
  float w = (tid < NP) ? __builtin_amdgcn_exp2f((ev - mx) * 1.44269504f) : 0.f;
  if (tid < 256) sm[tid] = w;
  __syncthreads();
  for (int s = 128; s > 0; s >>= 1) {
    if (tid < s) sm[tid] += sm[tid + s];
    __syncthreads();
  }
  float inv = __builtin_amdgcn_rcpf(sm[0]);
  if (tid < NP) alp[tid] = w * inv;
  __syncthreads();

  // ctx: 8 p-groups x 128 col-units of 8 (uint4 loads), LDS-reduce over p-groups
  {
    const int pg = tid >> 7, cu = tid & 127;
    const int col = ch * 1024 + cu * 8;
    const u16* base = cnnb + (size_t)b * NP * NE + col;
    float acc[8] = {};
    for (int i = 0; i < 25; ++i) {
      int p = pg + i * 8;
      if (p < NP) {
        float al = alp[p];
        uint4 raw = *(const uint4*)(base + (size_t)p * NE);
        u32 wds[4] = {raw.x, raw.y, raw.z, raw.w};
#pragma unroll
        for (int j = 0; j < 8; ++j)
          acc[j] += al * bf2f((u16)(wds[j >> 1] >> ((j & 1) * 16)));
      }
    }
#pragma unroll
    for (int j = 0; j < 8; ++j) red[tid * 8 + j] = acc[j];
    __syncthreads();
    if (tid < 512) {
      const int cu2 = tid >> 2, jp = tid & 3;
      float s0 = 0.f, s1 = 0.f;
#pragma unroll
      for (int g = 0; g < 8; ++g) {
        s0 += red[g * 1024 + cu2 * 8 + jp * 2];
        s1 += red[g * 1024 + cu2 * 8 + jp * 2 + 1];
      }
      u32 packed = (u32)f2bf(s0) | ((u32)f2bf(s1) << 16);
      *(u32*)(ctxb + (size_t)b * NE + ch * 1024 + cu2 * 8 + jp * 2) = packed;
    }
  }
}

// ---------------- gates GEMM (M=64,N=2048,K=2560) + LSTM cell + hWa partials ----------------
// grid 128: nt = blk & 31, mt = blk >> 5  (the 4 mt-blocks of one nt share an XCD L2 for B).
// 512 thr = 8 waves = (kh in {0,1}) x (gate g in {0..3}).
__global__ __launch_bounds__(512) void gates_kernel(
    const u16* __restrict__ hprev, const u16* __restrict__ ctxb, const u16* __restrict__ whct,
    const float* __restrict__ xw, const float* __restrict__ bi, const float* __restrict__ bfg,
    const float* __restrict__ bc, const float* __restrict__ bo, float* __restrict__ cbuf,
    float* __restrict__ out, const float* __restrict__ wah, u16* __restrict__ hwap,
    u16* __restrict__ hnext, int t) {
  int nt = blockIdx.x & 31, mt = blockIdx.x >> 5;
  int tid = threadIdx.x, lane = tid & 63, wid = tid >> 6;
  int g = wid & 3, kh = wid >> 2;
  int brow = mt * 16 + (lane & 15);
  int ncol = nt * 16 + (lane & 15);
  const u16* Bp = whct + (size_t)(g * 512 + ncol) * 2560;
  const u16* hA = hprev + (size_t)brow * 512;
  const u16* cA = ctxb + (size_t)brow * 2048 - 512;  // indexed by k in [512,2560)
  int klo = kh * 1280 + ((lane >> 4) * 8);
  f32x4 acc = {0.f, 0.f, 0.f, 0.f};
  if (kh == 0) {
    if (t > 0) {  // h == 0 at t == 0
#pragma unroll 4
      for (int ks = 0; ks < 16; ++ks) {
        int k = klo + ks * 32;
        bf16x8 a = *(const bf16x8*)(hA + k);
        bf16x8 bb = *(const bf16x8*)(Bp + k);
        acc = __builtin_amdgcn_mfma_f32_16x16x32_bf16(a, bb, acc, 0, 0, 0);
      }
    }
#pragma unroll 4
    for (int ks = 16; ks < 40; ++ks) {
      int k = klo + ks * 32;
      bf16x8 a = *(const bf16x8*)(cA + k);
      bf16x8 bb = *(const bf16x8*)(Bp + k);
      acc = __builtin_amdgcn_mfma_f32_16x16x32_bf16(a, bb, acc, 0, 0, 0);
    }
  } else {
#pragma unroll 4
    for (int ks = 0; ks < 40; ++ks) {
      int k = klo + ks * 32;
      bf16x8 a = *(const bf16x8*)(cA + k);
      bf16x8 bb = *(const bf16x8*)(Bp + k);
      acc = __builtin_amdgcn_mfma_f32_16x16x32_bf16(a, bb, acc, 0, 0, 0);
    }
  }

  __shared__ float pre[4][16][16];
  __shared__ float hlds[16][16];
  int rrow = (lane >> 4) * 4;
  if (kh == 0) {
#pragma unroll
    for (int r = 0; r < 4; ++r) pre[g][rrow + r][lane & 15] = acc[r];
  }
  __syncthreads();
  if (kh == 1) {
#pragma unroll
    for (int r = 0; r < 4; ++r) pre[g][rrow + r][lane & 15] += acc[r];
  }
  __syncthreads();

  if (tid < 256) {
    int m = tid >> 4, n = tid & 15;
    int b = mt * 16 + m, ng = nt * 16 + n;
    size_t xwo = ((size_t)t * NB + b) * 2048 + ng;  // xw layout [t][b][2048]
    float ip = pre[0][m][n] + xw[xwo] + bi[ng];
    float fp = pre[1][m][n] + xw[xwo + 512] + bfg[ng];
    float cp = pre[2][m][n] + xw[xwo + 1024] + bc[ng];
    float op = pre[3][m][n] + xw[xwo + 1536] + bo[ng];
    float it = sigmoid_fast(ip), ft = sigmoid_fast(fp), ot = sigmoid_fast(op);
    float ctl = tanh_fast(cp);
    float cold = (t > 0) ? cbuf[(size_t)b * 512 + ng] : 0.f;
    float cn = ft * cold + it * ctl;
    float hn = ot * tanh_fast(cn);
    cbuf[(size_t)b * 512 + ng] = cn;
    hnext[(size_t)b * 512 + ng] = f2bf(hn);
    out[((size_t)b * NT + t) * 512 + ng] = hn;
    if (t == NT - 1) {
      out[(size_t)NB * NT * 512 + (size_t)b * 512 + ng] = hn;
      out[(size_t)NB * NT * 512 + (size_t)NB * 512 + (size_t)b * 512 + ng] = cn;
    }
    hlds[m][n] = hn;
  }
  __syncthreads();

  // hWa partial: hwap[nt][b][a] = sum_{j<16} h[b][nt*16+j] * Wa_h[nt*16+j][a]  (bf16 out)
  {
    int a = tid;
    float wa[16];
#pragma unroll
    for (int j = 0; j < 16; ++j) wa[j] = wah[(size_t)(nt * 16 + j) * 512 + a];
#pragma unroll
    for (int bl = 0; bl < 16; ++bl) {
      float s = 0.f;
#pragma unroll
      for (int j = 0; j < 16; ++j) s += hlds[bl][j] * wa[j];
      hwap[((size_t)nt * 64 + mt * 16 + bl) * 512 + a] = f2bf(s);
    }
  }
}

// ======================= host launcher =======================
extern "C" void kernel_launch(void* const* d_in, const int* in_sizes, int n_in, void* d_out,
                              int out_size, void* d_ws, size_t ws_size, hipStream_t stream) {
  const float* x = (const float*)d_in[0];
  const float* cnn = (const float*)d_in[1];
  const float* Wi = (const float*)d_in[2];
  const float* bi = (const float*)d_in[3];
  const float* Wf = (const float*)d_in[4];
  const float* bfv = (const float*)d_in[5];
  const float* Wc = (const float*)d_in[6];
  const float* bc = (const float*)d_in[7];
  const float* Wo = (const float*)d_in[8];
  const float* bo = (const float*)d_in[9];
  const float* Waf = (const float*)d_in[10];
  const float* Wah = (const float*)d_in[11];
  const float* ba = (const float*)d_in[12];
  const float* v = (const float*)d_in[13];
  float* out = (float*)d_out;

  char* base = (char*)d_ws;
  size_t off = 0;
  auto alloc = [&](size_t bytes) {
    char* r = base + off;
    off += (bytes + 255) & ~(size_t)255;
    return r;
  };
  u16* cnnb = (u16*)alloc((size_t)NB * NP * NE * 2);       // 51.4 MB
  u16* fpb = (u16*)alloc((size_t)NB * NP * NA * 2);        // 12.8 MB
  u16* whct = (u16*)alloc((size_t)4 * 512 * 2560 * 2);     // 10.5 MB
  u16* wxt = (u16*)alloc((size_t)4 * 512 * 512 * 2);       // 2 MB
  u16* waft = (u16*)alloc((size_t)512 * 2048 * 2);         // 2 MB
  u16* xbT = (u16*)alloc((size_t)NT * NB * 512 * 2);       // 1.3 MB  [t][b][512]
  float* xw = (float*)alloc((size_t)NT * NB * 2048 * 4);   // 10.5 MB [t][b][2048]
  u16* hbuf = (u16*)alloc((size_t)2 * NB * 512 * 2);       // 128 KB (double buffer)
  float* cbuf = (float*)alloc((size_t)NB * 512 * 4);       // 128 KB
  u16* ctxb = (u16*)alloc((size_t)NB * 2048 * 2);          // 256 KB
  u16* hwap = (u16*)alloc((size_t)32 * NB * 512 * 2);      // 2 MB (bf16 partials)

  (void)ws_size;
  (void)in_sizes;
  (void)n_in;
  (void)out_size;

  // conversions / transposes
  conv_bf16<<<2048, 256, 0, stream>>>((const float4*)cnn, cnnb, (NB * NP * NE) / 4);
  conv_x<<<dim3(NB, NT), 128, 0, stream>>>(x, xbT);
  {
    dim3 g1(2560 / 32, 16, 4);
    transpose_w<<<g1, 256, 0, stream>>>(Wi, Wf, Wc, Wo, whct, 512, 2560);
    dim3 g2(512 / 32, 16, 4);
    transpose_w<<<g2, 256, 0, stream>>>(Wi, Wf, Wc, Wo, wxt, 0, 512);
    dim3 g3(2048 / 32, 16, 1);
    transpose_w<<<g3, 256, 0, stream>>>(Waf, Waf, Waf, Waf, waft, 0, 2048);
  }

  // feat_proj = cnn @ Wa_feat + ba  -> bf16 [12544][512]
  {
    dim3 g(12544 / 128, 512 / 128);
    gemm_bf16<true, true><<<g, 256, 0, stream>>>(cnnb, waft, ba, fpb, 12544, 512, 2048);
  }
  // xw = xT @ W[:512,:] (4 gates) -> f32 [t*64+b][2048]
  {
    dim3 g(1280 / 128, 2048 / 128);
    gemm_bf16<false, false><<<g, 256, 0, stream>>>(xbT, wxt, nullptr, xw, 1280, 2048, 512);
  }

  // 20-step recurrence: 2 kernels per step
  for (int t = 0; t < NT; ++t) {
    const u16* hprev = hbuf + (size_t)(t & 1) * NB * 512;
    u16* hnext = hbuf + (size_t)((t + 1) & 1) * NB * 512;
    attn_ctx<<<128, 1024, 0, stream>>>(fpb, hwap, v, cnnb, ctxb, t);
    gates_kernel<<<128, 512, 0, stream>>>(hprev, ctxb, whct, xw, bi, bfv, bc, bo, cbuf, out, Wah,
                                          hwap, hnext, t);
  }
}

// Round 6
// 763.713 us; speedup vs baseline: 2.0876x; 1.2690x over previous
//
#include <hip/hip_runtime.h>

typedef unsigned short u16;
typedef unsigned int u32;
typedef __attribute__((ext_vector_type(8))) short bf16x8;
typedef __attribute__((ext_vector_type(4))) float f32x4;

// B=64 T=20 D_IN=512 H=512 D_ENC=2048 P=196 D_ATT=512
#define NB 64
#define NT 20
#define NH 512
#define NP 196
#define NE 2048
#define NA 512

__device__ __forceinline__ u16 f2bf(float f) {
  u32 b = __float_as_uint(f);
  return (u16)((b + 0x7FFFu + ((b >> 16) & 1u)) >> 16);
}
__device__ __forceinline__ float bf2f(u16 u) { return __uint_as_float(((u32)u) << 16); }
__device__ __forceinline__ float tanh_fast(float x) {
  float xc = fminf(fmaxf(x, -15.f), 15.f);
  float e2 = __builtin_amdgcn_exp2f(xc * 2.885390082f);
  return (e2 - 1.f) * __builtin_amdgcn_rcpf(e2 + 1.f);
}
__device__ __forceinline__ float sigmoid_fast(float x) {
  return __builtin_amdgcn_rcpf(1.f + __builtin_amdgcn_exp2f(x * -1.44269504f));
}

// ---------------- f32 -> bf16 convert (vectorized, grid-stride) ----------------
__global__ __launch_bounds__(256) void conv_bf16(const float4* __restrict__ src,
                                                 u16* __restrict__ dst, int n4) {
  int i = blockIdx.x * 256 + threadIdx.x;
  int stride = gridDim.x * 256;
  for (; i < n4; i += stride) {
    float4 v = src[i];
    u32 lo = (u32)f2bf(v.x) | ((u32)f2bf(v.y) << 16);
    u32 hi = (u32)f2bf(v.z) | ((u32)f2bf(v.w) << 16);
    *(uint2*)(dst + (size_t)i * 4) = make_uint2(lo, hi);
  }
}

// ---------------- x [b][t][512] f32 -> xbT [t][b][512] bf16 ----------------
__global__ __launch_bounds__(128) void conv_x(const float* __restrict__ x,
                                              u16* __restrict__ xbT) {
  int b = blockIdx.x, t = blockIdx.y, tid = threadIdx.x;
  float4 v = *(const float4*)(x + ((size_t)b * NT + t) * 512 + tid * 4);
  u32 lo = (u32)f2bf(v.x) | ((u32)f2bf(v.y) << 16);
  u32 hi = (u32)f2bf(v.z) | ((u32)f2bf(v.w) << 16);
  *(uint2*)(xbT + ((size_t)t * NB + b) * 512 + tid * 4) = make_uint2(lo, hi);
}

// ------------- transpose f32 [K][512] (+row offset) -> bf16 [z*512+n][K] -------------
__global__ __launch_bounds__(256) void transpose_w(const float* __restrict__ W0,
                                                   const float* __restrict__ W1,
                                                   const float* __restrict__ W2,
                                                   const float* __restrict__ W3,
                                                   u16* __restrict__ dst, int row_off, int K) {
  const float* src = blockIdx.z == 0 ? W0 : blockIdx.z == 1 ? W1 : blockIdx.z == 2 ? W2 : W3;
  __shared__ float tile[32][33];
  int k0 = blockIdx.x * 32, n0 = blockIdx.y * 32;
  int tx = threadIdx.x & 31, ty = threadIdx.x >> 5;  // 32 x 8
#pragma unroll
  for (int i = 0; i < 4; ++i)
    tile[ty + i * 8][tx] = src[(size_t)(row_off + k0 + ty + i * 8) * 512 + n0 + tx];
  __syncthreads();
#pragma unroll
  for (int i = 0; i < 4; ++i) {
    int n = n0 + ty + i * 8, k = k0 + tx;
    dst[((size_t)blockIdx.z * 512 + n) * K + k] = f2bf(tile[tx][ty + i * 8]);
  }
}

// ------------- generic bf16 MFMA GEMM: C[M][N] = A[M][K] * BT[N][K]^T (+bias) -------------
// REMAP: m=(bdx,p) rows of [12544], n=(g,n') of [2048] -> bf16 out[((bdx*4+g)*196+p)*512+n']
template <bool OUT_BF16, bool BIAS, bool REMAP>
__global__ __launch_bounds__(256) void gemm_bf16(const u16* __restrict__ A,
                                                 const u16* __restrict__ BT,
                                                 const float* __restrict__ bias,
                                                 void* __restrict__ Cout, int M, int N, int K) {
  __shared__ u16 lA[128 * 64];
  __shared__ u16 lB[128 * 64];
  const int tid = threadIdx.x;
  const int lane = tid & 63;
  const int wid = tid >> 6;
  const int m0 = blockIdx.x * 128, n0 = blockIdx.y * 128;
  const int wm = (wid >> 1) * 64, wn = (wid & 1) * 64;
  f32x4 acc[4][4] = {};

  for (int k0 = 0; k0 < K; k0 += 64) {
    __syncthreads();
#pragma unroll
    for (int it = 0; it < 4; ++it) {
      int c = tid + it * 256;
      int r = c >> 3, c7 = c & 7;
      uint4 va = *(const uint4*)(A + (size_t)(m0 + r) * K + k0 + c7 * 8);
      uint4 vb = *(const uint4*)(BT + (size_t)(n0 + r) * K + k0 + c7 * 8);
      int ldsoff = r * 64 + ((c7 ^ (r & 7)) * 8);
      *(uint4*)(lA + ldsoff) = va;
      *(uint4*)(lB + ldsoff) = vb;
    }
    __syncthreads();
#pragma unroll
    for (int kk = 0; kk < 2; ++kk) {
      int kchunk = kk * 4 + (lane >> 4);
      bf16x8 af[4], bg[4];
#pragma unroll
      for (int i = 0; i < 4; ++i) {
        int row = wm + i * 16 + (lane & 15);
        af[i] = *(const bf16x8*)(lA + row * 64 + ((kchunk ^ (row & 7)) * 8));
        int rowb = wn + i * 16 + (lane & 15);
        bg[i] = *(const bf16x8*)(lB + rowb * 64 + ((kchunk ^ (rowb & 7)) * 8));
      }
#pragma unroll
      for (int i = 0; i < 4; ++i)
#pragma unroll
        for (int j = 0; j < 4; ++j)
          acc[i][j] = __builtin_amdgcn_mfma_f32_16x16x32_bf16(af[i], bg[j], acc[i][j], 0, 0, 0);
    }
  }
#pragma unroll
  for (int i = 0; i < 4; ++i) {
    int m = m0 + wm + i * 16 + ((lane >> 4) * 4);
#pragma unroll
    for (int j = 0; j < 4; ++j) {
      int n = n0 + wn + j * 16 + (lane & 15);
      float bv = BIAS ? bias[n] : 0.f;
#pragma unroll
      for (int r = 0; r < 4; ++r) {
        float val = acc[i][j][r] + bv;
        if (REMAP) {
          u32 me = (u32)(m + r);
          u32 bdx = me / 196u;
          u32 p = me - bdx * 196u;
          u32 g = (u32)n >> 9;
          u32 n9 = (u32)n & 511u;
          ((u16*)Cout)[(((size_t)bdx * 4 + g) * 196 + p) * 512 + n9] = f2bf(val);
        } else if (OUT_BF16) {
          ((u16*)Cout)[(size_t)(m + r) * N + n] = f2bf(val);
        } else {
          ((float*)Cout)[(size_t)(m + r) * N + n] = val;
        }
      }
    }
  }
}

// ---------------- hproj: hp[64][2560] = h[64][512] @ wcT[2560][512]^T (f32 out) ----------------
// grid 160 (16-col tiles), 256 thr = 4 waves on K-quarters of 128.
__global__ __launch_bounds__(256) void hproj(const u16* __restrict__ hprev,
                                             const u16* __restrict__ wcT,
                                             float* __restrict__ hp) {
  const int ntile = blockIdx.x;
  const int tid = threadIdx.x, lane = tid & 63, kh = tid >> 6;
  const int l15 = lane & 15;
  const u16* Bp = wcT + (size_t)(ntile * 16 + l15) * 512 + kh * 128 + ((lane >> 4) * 8);
  const u16* Ap = hprev + (size_t)l15 * 512 + kh * 128 + ((lane >> 4) * 8);
  f32x4 acc[4] = {};
#pragma unroll
  for (int ks = 0; ks < 4; ++ks) {
    bf16x8 bb = *(const bf16x8*)(Bp + ks * 32);
#pragma unroll
    for (int mf = 0; mf < 4; ++mf) {
      bf16x8 a = *(const bf16x8*)(Ap + (size_t)mf * 16 * 512 + ks * 32);
      acc[mf] = __builtin_amdgcn_mfma_f32_16x16x32_bf16(a, bb, acc[mf], 0, 0, 0);
    }
  }
  __shared__ float pre[4][64][16];
  const int rrow = (lane >> 4) * 4;
#pragma unroll
  for (int mf = 0; mf < 4; ++mf)
#pragma unroll
    for (int r = 0; r < 4; ++r) pre[kh][mf * 16 + rrow + r][l15] = acc[mf][r];
  __syncthreads();
  const int m = tid >> 2, n = (tid & 3) * 4;
  float4 s;
  float* sp = (float*)&s;
#pragma unroll
  for (int j = 0; j < 4; ++j)
    sp[j] = pre[0][m][n + j] + pre[1][m][n + j] + pre[2][m][n + j] + pre[3][m][n + j];
  *(float4*)(hp + (size_t)m * 2560 + ntile * 16 + n) = s;
}

// ====== attn_gates: e + softmax + (alpha @ cnnW) + cell, one block per (b, n-half) ======
// grid 128: b = blk & 63, half = blk >> 6 (both halves of b land on same XCD: blk%8 == b%8).
__global__ __launch_bounds__(1024) void attn_gates(
    const u16* __restrict__ fpb, const float* __restrict__ hp, const float* __restrict__ v,
    const u16* __restrict__ cw, const float* __restrict__ xw, const float* __restrict__ bi,
    const float* __restrict__ bfg, const float* __restrict__ bc, const float* __restrict__ bo,
    float* __restrict__ cbuf, float* __restrict__ out, u16* __restrict__ hnext, int t) {
  const int b = blockIdx.x & 63;
  const int half = blockIdx.x >> 6;
  const int tid = threadIdx.x;
  const int lane = tid & 63, wid = tid >> 6;
  __shared__ float smem_a[1024];  // [0..511] hwa, [512..1023] vv; later pre4[4][256]
  __shared__ float sm[256];
  __shared__ float alp[200];
  __shared__ float red[8192];  // e[] in [0..255] first, then partials [4][8][32][8]

  float* hwa = smem_a;
  float* vv = smem_a + 512;
  if (tid < 512) {
    hwa[tid] = (t > 0) ? hp[(size_t)b * 2560 + 2048 + tid] : 0.f;
    vv[tid] = v[tid];
  }
  if (tid >= 196 && tid < 256) red[tid] = -3e38f;
  __syncthreads();

  // ---- e[p] = sum_a tanh(fp + hwa) * v ----
  float hw[8], vr[8];
#pragma unroll
  for (int j = 0; j < 8; ++j) {
    hw[j] = hwa[lane * 8 + j];
    vr[j] = vv[lane * 8 + j];
  }
  for (int p = wid; p < NP; p += 16) {
    const u16* fp = fpb + ((size_t)b * NP + p) * 512 + lane * 8;
    uint4 raw = *(const uint4*)fp;
    u32 w[4] = {raw.x, raw.y, raw.z, raw.w};
    float part = 0.f;
#pragma unroll
    for (int j = 0; j < 8; ++j) {
      u16 u = (u16)(w[j >> 1] >> ((j & 1) * 16));
      part += tanh_fast(bf2f(u) + hw[j]) * vr[j];
    }
#pragma unroll
    for (int off = 32; off > 0; off >>= 1) part += __shfl_xor(part, off);
    if (lane == 0) red[p] = part;
  }
  __syncthreads();

  // ---- softmax over 196 ----
  float ev = (tid < 256) ? red[tid] : -3e38f;
  if (tid < 256) sm[tid] = ev;
  __syncthreads();
  for (int s = 128; s > 0; s >>= 1) {
    if (tid < s) sm[tid] = fmaxf(sm[tid], sm[tid + s]);
    __syncthreads();
  }
  float mx = sm[0];
  __syncthreads();
  float w = (tid < NP) ? __builtin_amdgcn_exp2f((ev - mx) * 1.44269504f) : 0.f;
  if (tid < 256) sm[tid] = w;
  __syncthreads();
  for (int s = 128; s > 0; s >>= 1) {
    if (tid < s) sm[tid] += sm[tid + s];
    __syncthreads();
  }
  float inv = __builtin_amdgcn_rcpf(sm[0]);
  if (tid < NP) alp[tid] = w * inv;
  __syncthreads();

  // ---- gate pre-activation: pre[g][n'] = sum_p alpha[p] * cnnW[b][g][p][half*256+n'] ----
  // 1024 thr = g(4) x pg(8) x colc(32), 8 cols each via uint4.
  {
    const int g = tid >> 8, pg = (tid >> 5) & 7, colc = tid & 31;
    const u16* base = cw + ((size_t)(b * 4 + g) * 196) * 512 + half * 256 + colc * 8;
    float acc[8] = {};
    for (int i = 0; i < 25; ++i) {
      int p = pg + i * 8;
      if (p < NP) {
        float al = alp[p];
        uint4 raw = *(const uint4*)(base + (size_t)p * 512);
        u32 wds[4] = {raw.x, raw.y, raw.z, raw.w};
#pragma unroll
        for (int j = 0; j < 8; ++j) acc[j] += al * bf2f((u16)(wds[j >> 1] >> ((j & 1) * 16)));
      }
    }
#pragma unroll
    for (int j = 0; j < 8; ++j) red[((g * 8 + pg) * 32 + colc) * 8 + j] = acc[j];
  }
  __syncthreads();

  // reduce over pg into pre4 (aliases smem_a; hw/vr already in regs)
  float* pre4 = smem_a;
  {
    const int g = tid >> 8, nn = tid & 255;
    float s = 0.f;
#pragma unroll
    for (int pg = 0; pg < 8; ++pg) s += red[((g * 8 + pg) * 32 + (nn >> 3)) * 8 + (nn & 7)];
    pre4[g * 256 + nn] = s;
  }
  __syncthreads();

  // ---- LSTM cell for this half's 256 columns ----
  if (tid < 256) {
    const int ng = half * 256 + tid;
    const size_t xwo = ((size_t)t * NB + b) * 2048;
    const size_t hpb = (size_t)b * 2560;
    float hwh0 = 0.f, hwh1 = 0.f, hwh2 = 0.f, hwh3 = 0.f;
    if (t > 0) {
      hwh0 = hp[hpb + ng];
      hwh1 = hp[hpb + 512 + ng];
      hwh2 = hp[hpb + 1024 + ng];
      hwh3 = hp[hpb + 1536 + ng];
    }
    float ip = pre4[0 * 256 + tid] + xw[xwo + ng] + hwh0 + bi[ng];
    float fp = pre4[1 * 256 + tid] + xw[xwo + 512 + ng] + hwh1 + bfg[ng];
    float cp = pre4[2 * 256 + tid] + xw[xwo + 1024 + ng] + hwh2 + bc[ng];
    float op = pre4[3 * 256 + tid] + xw[xwo + 1536 + ng] + hwh3 + bo[ng];
    float it = sigmoid_fast(ip), ft = sigmoid_fast(fp), ot = sigmoid_fast(op);
    float ctl = tanh_fast(cp);
    float cold = (t > 0) ? cbuf[(size_t)b * 512 + ng] : 0.f;
    float cn = ft * cold + it * ctl;
    float hn = ot * tanh_fast(cn);
    cbuf[(size_t)b * 512 + ng] = cn;
    hnext[(size_t)b * 512 + ng] = f2bf(hn);
    out[((size_t)b * NT + t) * 512 + ng] = hn;
    if (t == NT - 1) {
      out[(size_t)NB * NT * 512 + (size_t)b * 512 + ng] = hn;
      out[(size_t)NB * NT * 512 + (size_t)NB * 512 + (size_t)b * 512 + ng] = cn;
    }
  }
}

// ======================= host launcher =======================
extern "C" void kernel_launch(void* const* d_in, const int* in_sizes, int n_in, void* d_out,
                              int out_size, void* d_ws, size_t ws_size, hipStream_t stream) {
  const float* x = (const float*)d_in[0];
  const float* cnn = (const float*)d_in[1];
  const float* Wi = (const float*)d_in[2];
  const float* bi = (const float*)d_in[3];
  const float* Wf = (const float*)d_in[4];
  const float* bfv = (const float*)d_in[5];
  const float* Wc = (const float*)d_in[6];
  const float* bc = (const float*)d_in[7];
  const float* Wo = (const float*)d_in[8];
  const float* bo = (const float*)d_in[9];
  const float* Waf = (const float*)d_in[10];
  const float* Wah = (const float*)d_in[11];
  const float* ba = (const float*)d_in[12];
  const float* v = (const float*)d_in[13];
  float* out = (float*)d_out;

  char* base = (char*)d_ws;
  size_t off = 0;
  auto alloc = [&](size_t bytes) {
    char* r = base + off;
    off += (bytes + 255) & ~(size_t)255;
    return r;
  };
  u16* cnnb = (u16*)alloc((size_t)NB * NP * NE * 2);      // 51.4 MB
  u16* fpb = (u16*)alloc((size_t)NB * NP * NA * 2);       // 12.8 MB
  u16* cnW = (u16*)alloc((size_t)NB * 4 * NP * 512 * 2);  // 51.4 MB [b][g][p][n']
  u16* wctxT = (u16*)alloc((size_t)4 * 512 * 2048 * 2);   // 8.4 MB  [g*512+n][2048]
  u16* wcombT = (u16*)alloc((size_t)2560 * 512 * 2);      // 2.6 MB  [2048 hWh | 512 hWa][512]
  u16* wxt = (u16*)alloc((size_t)4 * 512 * 512 * 2);      // 2 MB
  u16* waft = (u16*)alloc((size_t)512 * 2048 * 2);        // 2 MB
  u16* xbT = (u16*)alloc((size_t)NT * NB * 512 * 2);      // 1.3 MB  [t][b][512]
  float* xw = (float*)alloc((size_t)NT * NB * 2048 * 4);  // 10.5 MB [t][b][2048]
  u16* hbuf = (u16*)alloc((size_t)2 * NB * 512 * 2);      // 128 KB (double buffer)
  float* cbuf = (float*)alloc((size_t)NB * 512 * 4);      // 128 KB
  float* hp = (float*)alloc((size_t)NB * 2560 * 4);       // 656 KB [b][hWh 2048 | hWa 512]

  (void)ws_size;
  (void)in_sizes;
  (void)n_in;
  (void)out_size;

  // conversions / transposes
  conv_bf16<<<2048, 256, 0, stream>>>((const float4*)cnn, cnnb, (NB * NP * NE) / 4);
  conv_x<<<dim3(NB, NT), 128, 0, stream>>>(x, xbT);
  {
    dim3 g1(512 / 32, 16, 4);   // wxt: x-part rows 0..511
    transpose_w<<<g1, 256, 0, stream>>>(Wi, Wf, Wc, Wo, wxt, 0, 512);
    dim3 g2(2048 / 32, 16, 1);  // waft: Wa_feat [2048][512] -> [512][2048]
    transpose_w<<<g2, 256, 0, stream>>>(Waf, Waf, Waf, Waf, waft, 0, 2048);
    dim3 g3(2048 / 32, 16, 4);  // wctxT: ctx-part rows 1024..3071
    transpose_w<<<g3, 256, 0, stream>>>(Wi, Wf, Wc, Wo, wctxT, 1024, 2048);
    dim3 g4(512 / 32, 16, 4);   // wcombT[0..2047]: h-part rows 512..1023
    transpose_w<<<g4, 256, 0, stream>>>(Wi, Wf, Wc, Wo, wcombT, 512, 512);
    dim3 g5(512 / 32, 16, 1);   // wcombT[2048..2559]: Wa_h
    transpose_w<<<g5, 256, 0, stream>>>(Wah, Wah, Wah, Wah, wcombT + (size_t)2048 * 512, 0, 512);
  }

  // feat_proj = cnn @ Wa_feat + ba  -> bf16 [12544][512]
  {
    dim3 g(12544 / 128, 512 / 128);
    gemm_bf16<true, true, false><<<g, 256, 0, stream>>>(cnnb, waft, ba, fpb, 12544, 512, 2048);
  }
  // xw = xT @ W[:512,:] (4 gates) -> f32 [t*64+b][2048]
  {
    dim3 g(1280 / 128, 2048 / 128);
    gemm_bf16<false, false, false><<<g, 256, 0, stream>>>(xbT, wxt, nullptr, xw, 1280, 2048, 512);
  }
  // cnnW = cnn @ W_ctx (4 gates) -> bf16 [b][g][p][512] (REMAP epilogue)
  {
    dim3 g(12544 / 128, 2048 / 128);
    gemm_bf16<true, false, true><<<g, 256, 0, stream>>>(cnnb, wctxT, nullptr, cnW, 12544, 2048,
                                                        2048);
  }

  // 20-step recurrence: hproj (t>0) + fused attn/gates
  for (int t = 0; t < NT; ++t) {
    const u16* hprev = hbuf + (size_t)(t & 1) * NB * 512;
    u16* hnext = hbuf + (size_t)((t + 1) & 1) * NB * 512;
    if (t > 0) hproj<<<160, 256, 0, stream>>>(hprev, wcombT, hp);
    attn_gates<<<128, 1024, 0, stream>>>(fpb, hp, v, cnW, xw, bi, bfv, bc, bo, cbuf, out, hnext,
                                         t);
  }
}

// Round 7
// 739.149 us; speedup vs baseline: 2.1569x; 1.0332x over previous
//
#include <hip/hip_runtime.h>

typedef unsigned short u16;
typedef unsigned int u32;
typedef __attribute__((ext_vector_type(8))) short bf16x8;
typedef __attribute__((ext_vector_type(4))) float f32x4;

// B=64 T=20 D_IN=512 H=512 D_ENC=2048 P=196 D_ATT=512
#define NB 64
#define NT 20
#define NH 512
#define NP 196
#define NE 2048
#define NA 512

__device__ __forceinline__ u16 f2bf(float f) {
  u32 b = __float_as_uint(f);
  return (u16)((b + 0x7FFFu + ((b >> 16) & 1u)) >> 16);
}
__device__ __forceinline__ float bf2f(u16 u) { return __uint_as_float(((u32)u) << 16); }
__device__ __forceinline__ float tanh_fast(float x) {
  float xc = fminf(fmaxf(x, -15.f), 15.f);
  float e2 = __builtin_amdgcn_exp2f(xc * 2.885390082f);
  return (e2 - 1.f) * __builtin_amdgcn_rcpf(e2 + 1.f);
}
__device__ __forceinline__ float sigmoid_fast(float x) {
  return __builtin_amdgcn_rcpf(1.f + __builtin_amdgcn_exp2f(x * -1.44269504f));
}

__device__ __forceinline__ void gload_lds16(const u16* g, u16* l) {
  __builtin_amdgcn_global_load_lds((const __attribute__((address_space(1))) void*)g,
                                   (__attribute__((address_space(3))) void*)l, 16, 0, 0);
}

// ---------------- f32 -> bf16 convert (vectorized, grid-stride) ----------------
__global__ __launch_bounds__(256) void conv_bf16(const float4* __restrict__ src,
                                                 u16* __restrict__ dst, int n4) {
  int i = blockIdx.x * 256 + threadIdx.x;
  int stride = gridDim.x * 256;
  for (; i < n4; i += stride) {
    float4 v = src[i];
    u32 lo = (u32)f2bf(v.x) | ((u32)f2bf(v.y) << 16);
    u32 hi = (u32)f2bf(v.z) | ((u32)f2bf(v.w) << 16);
    *(uint2*)(dst + (size_t)i * 4) = make_uint2(lo, hi);
  }
}

// ---------------- x [b][t][512] f32 -> xbT [t][b][512] bf16 ----------------
__global__ __launch_bounds__(128) void conv_x(const float* __restrict__ x,
                                              u16* __restrict__ xbT) {
  int b = blockIdx.x, t = blockIdx.y, tid = threadIdx.x;
  float4 v = *(const float4*)(x + ((size_t)b * NT + t) * 512 + tid * 4);
  u32 lo = (u32)f2bf(v.x) | ((u32)f2bf(v.y) << 16);
  u32 hi = (u32)f2bf(v.z) | ((u32)f2bf(v.w) << 16);
  *(uint2*)(xbT + ((size_t)t * NB + b) * 512 + tid * 4) = make_uint2(lo, hi);
}

// ------------- transpose f32 [K][512] (+row offset) -> bf16 [z*512+n][K] -------------
__global__ __launch_bounds__(256) void transpose_w(const float* __restrict__ W0,
                                                   const float* __restrict__ W1,
                                                   const float* __restrict__ W2,
                                                   const float* __restrict__ W3,
                                                   u16* __restrict__ dst, int row_off, int K) {
  const float* src = blockIdx.z == 0 ? W0 : blockIdx.z == 1 ? W1 : blockIdx.z == 2 ? W2 : W3;
  __shared__ float tile[32][33];
  int k0 = blockIdx.x * 32, n0 = blockIdx.y * 32;
  int tx = threadIdx.x & 31, ty = threadIdx.x >> 5;  // 32 x 8
#pragma unroll
  for (int i = 0; i < 4; ++i)
    tile[ty + i * 8][tx] = src[(size_t)(row_off + k0 + ty + i * 8) * 512 + n0 + tx];
  __syncthreads();
#pragma unroll
  for (int i = 0; i < 4; ++i) {
    int n = n0 + ty + i * 8, k = k0 + tx;
    dst[((size_t)blockIdx.z * 512 + n) * K + k] = f2bf(tile[tx][ty + i * 8]);
  }
}

// ------------- bf16 MFMA GEMM, global_load_lds staging: C = A[M][K] * BT[N][K]^T -------------
// 128x128 tile, BK=64, 4 waves. LDS linear dest + inverse-XOR-swizzled per-lane global source
// (rule: source permutation == read permutation). MERGED: n<512 -> fpb(+ba), n>=512 -> cnW remap.
template <bool MERGED, bool OUT_BF16, bool BIAS>
__global__ __launch_bounds__(256) void gemm_bf16(const u16* __restrict__ A,
                                                 const u16* __restrict__ BT,
                                                 const float* __restrict__ bias,
                                                 void* __restrict__ C0, u16* __restrict__ C1,
                                                 int M, int N, int K) {
  __shared__ u16 lA[128 * 64];
  __shared__ u16 lB[128 * 64];
  const int tid = threadIdx.x;
  const int lane = tid & 63;
  const int wid = tid >> 6;
  const int m0 = blockIdx.x * 128, n0 = blockIdx.y * 128;
  const int wm = (wid >> 1) * 64, wn = (wid & 1) * 64;
  f32x4 acc[4][4] = {};

  // staging geometry: 16B chunk c in [0,1024): row r=c>>3, col-chunk cc=c&7.
  // LDS[c] receives global chunk (r, cc ^ (r&7)) so swizzled ds_read lands on (row, kchunk).
  const int cbase = wid * 256;  // wave-uniform
  int srcr[4], srcc[4];
#pragma unroll
  for (int it = 0; it < 4; ++it) {
    int c = cbase + it * 64 + lane;
    srcr[it] = c >> 3;
    srcc[it] = ((c & 7) ^ ((c >> 3) & 7)) * 8;
  }

  for (int k0 = 0; k0 < K; k0 += 64) {
    __syncthreads();
#pragma unroll
    for (int it = 0; it < 4; ++it) {
      const u16* sA = A + (size_t)(m0 + srcr[it]) * K + k0 + srcc[it];
      const u16* sB = BT + (size_t)(n0 + srcr[it]) * K + k0 + srcc[it];
      gload_lds16(sA, lA + (size_t)(cbase + it * 64) * 8);
      gload_lds16(sB, lB + (size_t)(cbase + it * 64) * 8);
    }
    __syncthreads();
#pragma unroll
    for (int kk = 0; kk < 2; ++kk) {
      int kchunk = kk * 4 + (lane >> 4);
      bf16x8 af[4], bg[4];
#pragma unroll
      for (int i = 0; i < 4; ++i) {
        int row = wm + i * 16 + (lane & 15);
        af[i] = *(const bf16x8*)(lA + row * 64 + ((kchunk ^ (row & 7)) * 8));
        int rowb = wn + i * 16 + (lane & 15);
        bg[i] = *(const bf16x8*)(lB + rowb * 64 + ((kchunk ^ (rowb & 7)) * 8));
      }
#pragma unroll
      for (int i = 0; i < 4; ++i)
#pragma unroll
        for (int j = 0; j < 4; ++j)
          acc[i][j] = __builtin_amdgcn_mfma_f32_16x16x32_bf16(af[i], bg[j], acc[i][j], 0, 0, 0);
    }
  }
#pragma unroll
  for (int i = 0; i < 4; ++i) {
    int m = m0 + wm + i * 16 + ((lane >> 4) * 4);
#pragma unroll
    for (int j = 0; j < 4; ++j) {
      int n = n0 + wn + j * 16 + (lane & 15);
      float bv = 0.f;
      if (BIAS && (!MERGED || n < 512)) bv = bias[n];
#pragma unroll
      for (int r = 0; r < 4; ++r) {
        float val = acc[i][j][r] + bv;
        if (MERGED) {
          u32 me = (u32)(m + r);
          if (n < 512) {
            ((u16*)C0)[(size_t)me * 512 + n] = f2bf(val);
          } else {
            u32 bdx = me / 196u;
            u32 p = me - bdx * 196u;
            u32 g = (u32)(n - 512) >> 9;
            u32 n9 = (u32)(n - 512) & 511u;
            C1[(((size_t)bdx * 4 + g) * 196 + p) * 512 + n9] = f2bf(val);
          }
        } else if (OUT_BF16) {
          ((u16*)C0)[(size_t)(m + r) * N + n] = f2bf(val);
        } else {
          ((float*)C0)[(size_t)(m + r) * N + n] = val;
        }
      }
    }
  }
}

// ---------------- hproj: hp[64][2560] = h[64][512] @ wcT[2560][512]^T (f32 out) ----------------
// grid 160 (16-col tiles), 256 thr = 4 waves on K-quarters of 128.
__global__ __launch_bounds__(256) void hproj(const u16* __restrict__ hprev,
                                             const u16* __restrict__ wcT,
                                             float* __restrict__ hp) {
  const int ntile = blockIdx.x;
  const int tid = threadIdx.x, lane = tid & 63, kh = tid >> 6;
  const int l15 = lane & 15;
  const u16* Bp = wcT + (size_t)(ntile * 16 + l15) * 512 + kh * 128 + ((lane >> 4) * 8);
  const u16* Ap = hprev + (size_t)l15 * 512 + kh * 128 + ((lane >> 4) * 8);
  f32x4 acc[4] = {};
#pragma unroll
  for (int ks = 0; ks < 4; ++ks) {
    bf16x8 bb = *(const bf16x8*)(Bp + ks * 32);
#pragma unroll
    for (int mf = 0; mf < 4; ++mf) {
      bf16x8 a = *(const bf16x8*)(Ap + (size_t)mf * 16 * 512 + ks * 32);
      acc[mf] = __builtin_amdgcn_mfma_f32_16x16x32_bf16(a, bb, acc[mf], 0, 0, 0);
    }
  }
  __shared__ float pre[4][64][16];
  const int rrow = (lane >> 4) * 4;
#pragma unroll
  for (int mf = 0; mf < 4; ++mf)
#pragma unroll
    for (int r = 0; r < 4; ++r) pre[kh][mf * 16 + rrow + r][l15] = acc[mf][r];
  __syncthreads();
  const int m = tid >> 2, n = (tid & 3) * 4;
  float4 s;
  float* sp = (float*)&s;
#pragma unroll
  for (int j = 0; j < 4; ++j)
    sp[j] = pre[0][m][n + j] + pre[1][m][n + j] + pre[2][m][n + j] + pre[3][m][n + j];
  *(float4*)(hp + (size_t)m * 2560 + ntile * 16 + n) = s;
}

// ====== attn_gates: e + softmax + (alpha @ cnnW) + cell, one block per (b, n-half) ======
// grid 128: b = blk & 63, half = blk >> 6 (both halves of b land on same XCD: blk%8 == b%8).
__global__ __launch_bounds__(1024) void attn_gates(
    const u16* __restrict__ fpb, const float* __restrict__ hp, const float* __restrict__ v,
    const u16* __restrict__ cw, const float* __restrict__ xw, const float* __restrict__ bi,
    const float* __restrict__ bfg, const float* __restrict__ bc, const float* __restrict__ bo,
    float* __restrict__ cbuf, float* __restrict__ out, u16* __restrict__ hnext, int t) {
  const int b = blockIdx.x & 63;
  const int half = blockIdx.x >> 6;
  const int tid = threadIdx.x;
  const int lane = tid & 63, wid = tid >> 6;
  __shared__ float smem_a[1024];  // [0..511] hwa, [512..1023] vv; later pre4[4][256]
  __shared__ float sm[16];
  __shared__ float alp[200];
  __shared__ float red[8192];  // e[] in [0..255] first, then partials [4][8][32][8]

  float* hwa = smem_a;
  float* vv = smem_a + 512;
  if (tid < 512) {
    hwa[tid] = (t > 0) ? hp[(size_t)b * 2560 + 2048 + tid] : 0.f;
    vv[tid] = v[tid];
  }
  if (tid >= 196 && tid < 256) red[tid] = -3e38f;
  __syncthreads();

  // ---- e[p] = sum_a tanh(fp + hwa) * v ----
  float hw[8], vr[8];
#pragma unroll
  for (int j = 0; j < 8; ++j) {
    hw[j] = hwa[lane * 8 + j];
    vr[j] = vv[lane * 8 + j];
  }
  for (int p = wid; p < NP; p += 16) {
    const u16* fp = fpb + ((size_t)b * NP + p) * 512 + lane * 8;
    uint4 raw = *(const uint4*)fp;
    u32 w[4] = {raw.x, raw.y, raw.z, raw.w};
    float part = 0.f;
#pragma unroll
    for (int j = 0; j < 8; ++j) {
      u16 u = (u16)(w[j >> 1] >> ((j & 1) * 16));
      part += tanh_fast(bf2f(u) + hw[j]) * vr[j];
    }
#pragma unroll
    for (int off = 32; off > 0; off >>= 1) part += __shfl_xor(part, off);
    if (lane == 0) red[p] = part;
  }
  __syncthreads();

  // ---- softmax over 196: wave-level reduce (4 waves hold the 256 padded e-values) ----
  float ev = 0.f, w = 0.f;
  if (tid < 256) {
    ev = red[tid];
    float m_ = ev;
#pragma unroll
    for (int off = 32; off > 0; off >>= 1) m_ = fmaxf(m_, __shfl_xor(m_, off));
    if (lane == 0) sm[wid] = m_;
  }
  __syncthreads();
  if (tid < 256) {
    float mx = fmaxf(fmaxf(sm[0], sm[1]), fmaxf(sm[2], sm[3]));
    w = (tid < NP) ? __builtin_amdgcn_exp2f((ev - mx) * 1.44269504f) : 0.f;
    float s_ = w;
#pragma unroll
    for (int off = 32; off > 0; off >>= 1) s_ += __shfl_xor(s_, off);
    if (lane == 0) sm[8 + wid] = s_;
  }
  __syncthreads();
  if (tid < NP) {
    float tot = (sm[8] + sm[9]) + (sm[10] + sm[11]);
    alp[tid] = w * __builtin_amdgcn_rcpf(tot);
  }
  __syncthreads();

  // ---- gate pre-activation: pre[g][n'] = sum_p alpha[p] * cnnW[b][g][p][half*256+n'] ----
  // 1024 thr = g(4) x pg(8) x colc(32), 8 cols each via uint4.
  {
    const int g = tid >> 8, pg = (tid >> 5) & 7, colc = tid & 31;
    const u16* base = cw + ((size_t)(b * 4 + g) * 196) * 512 + half * 256 + colc * 8;
    float acc[8] = {};
    for (int i = 0; i < 25; ++i) {
      int p = pg + i * 8;
      if (p < NP) {
        float al = alp[p];
        uint4 raw = *(const uint4*)(base + (size_t)p * 512);
        u32 wds[4] = {raw.x, raw.y, raw.z, raw.w};
#pragma unroll
        for (int j = 0; j < 8; ++j) acc[j] += al * bf2f((u16)(wds[j >> 1] >> ((j & 1) * 16)));
      }
    }
#pragma unroll
    for (int j = 0; j < 8; ++j) red[((g * 8 + pg) * 32 + colc) * 8 + j] = acc[j];
  }
  __syncthreads();

  // reduce over pg into pre4 (aliases smem_a; hw/vr already in regs)
  float* pre4 = smem_a;
  {
    const int g = tid >> 8, nn = tid & 255;
    float s = 0.f;
#pragma unroll
    for (int pg = 0; pg < 8; ++pg) s += red[((g * 8 + pg) * 32 + (nn >> 3)) * 8 + (nn & 7)];
    pre4[g * 256 + nn] = s;
  }
  __syncthreads();

  // ---- LSTM cell for this half's 256 columns ----
  if (tid < 256) {
    const int ng = half * 256 + tid;
    const size_t xwo = ((size_t)t * NB + b) * 2048;
    const size_t hpb = (size_t)b * 2560;
    float hwh0 = 0.f, hwh1 = 0.f, hwh2 = 0.f, hwh3 = 0.f;
    if (t > 0) {
      hwh0 = hp[hpb + ng];
      hwh1 = hp[hpb + 512 + ng];
      hwh2 = hp[hpb + 1024 + ng];
      hwh3 = hp[hpb + 1536 + ng];
    }
    float ip = pre4[0 * 256 + tid] + xw[xwo + ng] + hwh0 + bi[ng];
    float fp = pre4[1 * 256 + tid] + xw[xwo + 512 + ng] + hwh1 + bfg[ng];
    float cp = pre4[2 * 256 + tid] + xw[xwo + 1024 + ng] + hwh2 + bc[ng];
    float op = pre4[3 * 256 + tid] + xw[xwo + 1536 + ng] + hwh3 + bo[ng];
    float it = sigmoid_fast(ip), ft = sigmoid_fast(fp), ot = sigmoid_fast(op);
    float ctl = tanh_fast(cp);
    float cold = (t > 0) ? cbuf[(size_t)b * 512 + ng] : 0.f;
    float cn = ft * cold + it * ctl;
    float hn = ot * tanh_fast(cn);
    cbuf[(size_t)b * 512 + ng] = cn;
    hnext[(size_t)b * 512 + ng] = f2bf(hn);
    out[((size_t)b * NT + t) * 512 + ng] = hn;
    if (t == NT - 1) {
      out[(size_t)NB * NT * 512 + (size_t)b * 512 + ng] = hn;
      out[(size_t)NB * NT * 512 + (size_t)NB * 512 + (size_t)b * 512 + ng] = cn;
    }
  }
}

// ======================= host launcher =======================
extern "C" void kernel_launch(void* const* d_in, const int* in_sizes, int n_in, void* d_out,
                              int out_size, void* d_ws, size_t ws_size, hipStream_t stream) {
  const float* x = (const float*)d_in[0];
  const float* cnn = (const float*)d_in[1];
  const float* Wi = (const float*)d_in[2];
  const float* bi = (const float*)d_in[3];
  const float* Wf = (const float*)d_in[4];
  const float* bfv = (const float*)d_in[5];
  const float* Wc = (const float*)d_in[6];
  const float* bc = (const float*)d_in[7];
  const float* Wo = (const float*)d_in[8];
  const float* bo = (const float*)d_in[9];
  const float* Waf = (const float*)d_in[10];
  const float* Wah = (const float*)d_in[11];
  const float* ba = (const float*)d_in[12];
  const float* v = (const float*)d_in[13];
  float* out = (float*)d_out;

  char* base = (char*)d_ws;
  size_t off = 0;
  auto alloc = [&](size_t bytes) {
    char* r = base + off;
    off += (bytes + 255) & ~(size_t)255;
    return r;
  };
  u16* cnnb = (u16*)alloc((size_t)NB * NP * NE * 2);      // 51.4 MB
  u16* fpb = (u16*)alloc((size_t)NB * NP * NA * 2);       // 12.8 MB
  u16* cnW = (u16*)alloc((size_t)NB * 4 * NP * 512 * 2);  // 51.4 MB [b][g][p][n']
  u16* wbig = (u16*)alloc((size_t)2560 * 2048 * 2);       // 10.5 MB [512 Wa_feat^T | 2048 Wctx^T]
  u16* wcombT = (u16*)alloc((size_t)2560 * 512 * 2);      // 2.6 MB  [2048 hWh | 512 hWa][512]
  u16* wxt = (u16*)alloc((size_t)4 * 512 * 512 * 2);      // 2 MB
  u16* xbT = (u16*)alloc((size_t)NT * NB * 512 * 2);      // 1.3 MB  [t][b][512]
  float* xw = (float*)alloc((size_t)NT * NB * 2048 * 4);  // 10.5 MB [t][b][2048]
  u16* hbuf = (u16*)alloc((size_t)2 * NB * 512 * 2);      // 128 KB (double buffer)
  float* cbuf = (float*)alloc((size_t)NB * 512 * 4);      // 128 KB
  float* hp = (float*)alloc((size_t)NB * 2560 * 4);       // 656 KB [b][hWh 2048 | hWa 512]

  (void)ws_size;
  (void)in_sizes;
  (void)n_in;
  (void)out_size;

  // conversions / transposes
  conv_bf16<<<2048, 256, 0, stream>>>((const float4*)cnn, cnnb, (NB * NP * NE) / 4);
  conv_x<<<dim3(NB, NT), 128, 0, stream>>>(x, xbT);
  {
    dim3 g1(512 / 32, 16, 4);   // wxt: x-part rows 0..511
    transpose_w<<<g1, 256, 0, stream>>>(Wi, Wf, Wc, Wo, wxt, 0, 512);
    dim3 g2(2048 / 32, 16, 1);  // wbig rows 0..511: Wa_feat^T
    transpose_w<<<g2, 256, 0, stream>>>(Waf, Waf, Waf, Waf, wbig, 0, 2048);
    dim3 g3(2048 / 32, 16, 4);  // wbig rows 512..2559: ctx-part of W (rows 1024..3071)
    transpose_w<<<g3, 256, 0, stream>>>(Wi, Wf, Wc, Wo, wbig + (size_t)512 * 2048, 1024, 2048);
    dim3 g4(512 / 32, 16, 4);   // wcombT[0..2047]: h-part rows 512..1023
    transpose_w<<<g4, 256, 0, stream>>>(Wi, Wf, Wc, Wo, wcombT, 512, 512);
    dim3 g5(512 / 32, 16, 1);   // wcombT[2048..2559]: Wa_h
    transpose_w<<<g5, 256, 0, stream>>>(Wah, Wah, Wah, Wah, wcombT + (size_t)2048 * 512, 0, 512);
  }

  // merged: [fpb | cnW] = cnnb @ [Wa_feat^T | Wctx^T]  (M=12544, N=2560, K=2048)
  {
    dim3 g(12544 / 128, 2560 / 128);
    gemm_bf16<true, true, true><<<g, 256, 0, stream>>>(cnnb, wbig, ba, fpb, cnW, 12544, 2560,
                                                       2048);
  }
  // xw = xT @ W[:512,:] (4 gates) -> f32 [t*64+b][2048]
  {
    dim3 g(1280 / 128, 2048 / 128);
    gemm_bf16<false, false, false><<<g, 256, 0, stream>>>(xbT, wxt, nullptr, xw, nullptr, 1280,
                                                          2048, 512);
  }

  // 20-step recurrence: hproj (t>0) + fused attn/gates
  for (int t = 0; t < NT; ++t) {
    const u16* hprev = hbuf + (size_t)(t & 1) * NB * 512;
    u16* hnext = hbuf + (size_t)((t + 1) & 1) * NB * 512;
    if (t > 0) hproj<<<160, 256, 0, stream>>>(hprev, wcombT, hp);
    attn_gates<<<128, 1024, 0, stream>>>(fpb, hp, v, cnW, xw, bi, bfv, bc, bo, cbuf, out, hnext,
                                         t);
  }
}

// Round 8
// 706.553 us; speedup vs baseline: 2.2565x; 1.0461x over previous
//
#include <hip/hip_runtime.h>

typedef unsigned short u16;
typedef unsigned int u32;
typedef __attribute__((ext_vector_type(8))) short bf16x8;
typedef __attribute__((ext_vector_type(4))) float f32x4;

// B=64 T=20 D_IN=512 H=512 D_ENC=2048 P=196 D_ATT=512
#define NB 64
#define NT 20
#define NH 512
#define NP 196
#define NE 2048
#define NA 512

__device__ __forceinline__ u16 f2bf(float f) {
  u32 b = __float_as_uint(f);
  return (u16)((b + 0x7FFFu + ((b >> 16) & 1u)) >> 16);
}
__device__ __forceinline__ float bf2f(u16 u) { return __uint_as_float(((u32)u) << 16); }
__device__ __forceinline__ float tanh_fast(float x) {
  float xc = fminf(fmaxf(x, -15.f), 15.f);
  float e2 = __builtin_amdgcn_exp2f(xc * 2.885390082f);
  return (e2 - 1.f) * __builtin_amdgcn_rcpf(e2 + 1.f);
}
__device__ __forceinline__ float sigmoid_fast(float x) {
  return __builtin_amdgcn_rcpf(1.f + __builtin_amdgcn_exp2f(x * -1.44269504f));
}

__device__ __forceinline__ void gload_lds16(const u16* g, u16* l) {
  __builtin_amdgcn_global_load_lds((const __attribute__((address_space(1))) void*)g,
                                   (__attribute__((address_space(3))) void*)l, 16, 0, 0);
}

// ---------------- f32 -> bf16 convert (vectorized, grid-stride) ----------------
__global__ __launch_bounds__(256) void conv_bf16(const float4* __restrict__ src,
                                                 u16* __restrict__ dst, int n4) {
  int i = blockIdx.x * 256 + threadIdx.x;
  int stride = gridDim.x * 256;
  for (; i < n4; i += stride) {
    float4 v = src[i];
    u32 lo = (u32)f2bf(v.x) | ((u32)f2bf(v.y) << 16);
    u32 hi = (u32)f2bf(v.z) | ((u32)f2bf(v.w) << 16);
    *(uint2*)(dst + (size_t)i * 4) = make_uint2(lo, hi);
  }
}

// ---------------- x [b][t][512] f32 -> xbT [t][b][512] bf16 ----------------
__global__ __launch_bounds__(128) void conv_x(const float* __restrict__ x,
                                              u16* __restrict__ xbT) {
  int b = blockIdx.x, t = blockIdx.y, tid = threadIdx.x;
  float4 v = *(const float4*)(x + ((size_t)b * NT + t) * 512 + tid * 4);
  u32 lo = (u32)f2bf(v.x) | ((u32)f2bf(v.y) << 16);
  u32 hi = (u32)f2bf(v.z) | ((u32)f2bf(v.w) << 16);
  *(uint2*)(xbT + ((size_t)t * NB + b) * 512 + tid * 4) = make_uint2(lo, hi);
}

// ------------- transpose f32 [K][512] (+row offset) -> bf16 [z*512+n][K] -------------
__global__ __launch_bounds__(256) void transpose_w(const float* __restrict__ W0,
                                                   const float* __restrict__ W1,
                                                   const float* __restrict__ W2,
                                                   const float* __restrict__ W3,
                                                   u16* __restrict__ dst, int row_off, int K) {
  const float* src = blockIdx.z == 0 ? W0 : blockIdx.z == 1 ? W1 : blockIdx.z == 2 ? W2 : W3;
  __shared__ float tile[32][33];
  int k0 = blockIdx.x * 32, n0 = blockIdx.y * 32;
  int tx = threadIdx.x & 31, ty = threadIdx.x >> 5;  // 32 x 8
#pragma unroll
  for (int i = 0; i < 4; ++i)
    tile[ty + i * 8][tx] = src[(size_t)(row_off + k0 + ty + i * 8) * 512 + n0 + tx];
  __syncthreads();
#pragma unroll
  for (int i = 0; i < 4; ++i) {
    int n = n0 + ty + i * 8, k = k0 + tx;
    dst[((size_t)blockIdx.z * 512 + n) * K + k] = f2bf(tile[tx][ty + i * 8]);
  }
}

// ------------- 128^2 bf16 MFMA GEMM (global_load_lds staging), f32 out: xw -------------
__global__ __launch_bounds__(256) void gemm_bf16(const u16* __restrict__ A,
                                                 const u16* __restrict__ BT,
                                                 float* __restrict__ C, int M, int N, int K) {
  __shared__ u16 lA[128 * 64];
  __shared__ u16 lB[128 * 64];
  const int tid = threadIdx.x;
  const int lane = tid & 63;
  const int wid = tid >> 6;
  const int m0 = blockIdx.x * 128, n0 = blockIdx.y * 128;
  const int wm = (wid >> 1) * 64, wn = (wid & 1) * 64;
  f32x4 acc[4][4] = {};

  const int cbase = wid * 256;  // wave-uniform
  int srcr[4], srcc[4];
#pragma unroll
  for (int it = 0; it < 4; ++it) {
    int c = cbase + it * 64 + lane;
    srcr[it] = c >> 3;
    srcc[it] = ((c & 7) ^ ((c >> 3) & 7)) * 8;
  }

  for (int k0 = 0; k0 < K; k0 += 64) {
    __syncthreads();
#pragma unroll
    for (int it = 0; it < 4; ++it) {
      gload_lds16(A + (size_t)(m0 + srcr[it]) * K + k0 + srcc[it],
                  lA + (size_t)(cbase + it * 64) * 8);
      gload_lds16(BT + (size_t)(n0 + srcr[it]) * K + k0 + srcc[it],
                  lB + (size_t)(cbase + it * 64) * 8);
    }
    __syncthreads();
#pragma unroll
    for (int kk = 0; kk < 2; ++kk) {
      int kchunk = kk * 4 + (lane >> 4);
      bf16x8 af[4], bg[4];
#pragma unroll
      for (int i = 0; i < 4; ++i) {
        int row = wm + i * 16 + (lane & 15);
        af[i] = *(const bf16x8*)(lA + row * 64 + ((kchunk ^ (row & 7)) * 8));
        int rowb = wn + i * 16 + (lane & 15);
        bg[i] = *(const bf16x8*)(lB + rowb * 64 + ((kchunk ^ (rowb & 7)) * 8));
      }
#pragma unroll
      for (int i = 0; i < 4; ++i)
#pragma unroll
        for (int j = 0; j < 4; ++j)
          acc[i][j] = __builtin_amdgcn_mfma_f32_16x16x32_bf16(af[i], bg[j], acc[i][j], 0, 0, 0);
    }
  }
#pragma unroll
  for (int i = 0; i < 4; ++i) {
    int m = m0 + wm + i * 16 + ((lane >> 4) * 4);
#pragma unroll
    for (int j = 0; j < 4; ++j) {
      int n = n0 + wn + j * 16 + (lane & 15);
#pragma unroll
      for (int r = 0; r < 4; ++r) C[(size_t)(m + r) * N + n] = acc[i][j][r];
    }
  }
}

// ------- 256^2 bf16 MFMA GEMM, merged epilogue: n<512 -> fpb(+ba), n>=512 -> cnW remap -------
// 512 thr = 8 waves (2M x 4N), wave tile 128x64 = acc[8][4]. BK=64. XCD-bijective swizzle.
__global__ __launch_bounds__(512, 2) void gemm256(const u16* __restrict__ A,
                                                  const u16* __restrict__ BT,
                                                  const float* __restrict__ bias,
                                                  u16* __restrict__ fpb, u16* __restrict__ cnW,
                                                  int K, int grid_n) {
  __shared__ u16 lA[256 * 64];
  __shared__ u16 lB[256 * 64];
  const int tid = threadIdx.x;
  const int lane = tid & 63;
  const int wid = tid >> 6;
  // bijective XCD-chunked swizzle (m204): consecutive swz share an XCD; nt-fastest
  const int nblk = gridDim.x;
  const int q = nblk >> 3, rr = nblk & 7;
  const int xcd = blockIdx.x & 7, jj = blockIdx.x >> 3;
  const int swz = (xcd < rr ? xcd * (q + 1) : rr * (q + 1) + (xcd - rr) * q) + jj;
  const int mt = swz / grid_n, nt = swz - mt * grid_n;
  const int m0 = mt * 256, n0 = nt * 256;
  const int wm = (wid >> 2) * 128, wn = (wid & 3) * 64;
  f32x4 acc[8][4] = {};

  // staging: 2048 16B-chunks per tile; 512 thr x 4 its. chunk c: r=c>>3, cc=c&7.
  const int cbase = wid * 64;  // within an it-slab of 512 chunks, wave-uniform
  int srcr[4], srcc[4];
#pragma unroll
  for (int it = 0; it < 4; ++it) {
    int c = it * 512 + cbase + lane;
    srcr[it] = c >> 3;
    srcc[it] = ((c & 7) ^ ((c >> 3) & 7)) * 8;
  }

  for (int k0 = 0; k0 < K; k0 += 64) {
    __syncthreads();
#pragma unroll
    for (int it = 0; it < 4; ++it) {
      int ldso = (it * 512 + cbase) * 8;
      gload_lds16(A + (size_t)(m0 + srcr[it]) * K + k0 + srcc[it], lA + ldso);
      gload_lds16(BT + (size_t)(n0 + srcr[it]) * K + k0 + srcc[it], lB + ldso);
    }
    __syncthreads();
#pragma unroll
    for (int kk = 0; kk < 2; ++kk) {
      int kchunk = kk * 4 + (lane >> 4);
      bf16x8 af[8], bg[4];
#pragma unroll
      for (int i = 0; i < 8; ++i) {
        int row = wm + i * 16 + (lane & 15);
        af[i] = *(const bf16x8*)(lA + row * 64 + ((kchunk ^ (row & 7)) * 8));
      }
#pragma unroll
      for (int j = 0; j < 4; ++j) {
        int rowb = wn + j * 16 + (lane & 15);
        bg[j] = *(const bf16x8*)(lB + rowb * 64 + ((kchunk ^ (rowb & 7)) * 8));
      }
#pragma unroll
      for (int i = 0; i < 8; ++i)
#pragma unroll
        for (int j = 0; j < 4; ++j)
          acc[i][j] = __builtin_amdgcn_mfma_f32_16x16x32_bf16(af[i], bg[j], acc[i][j], 0, 0, 0);
    }
  }

#pragma unroll
  for (int i = 0; i < 8; ++i) {
    int m = m0 + wm + i * 16 + ((lane >> 4) * 4);
#pragma unroll
    for (int j = 0; j < 4; ++j) {
      int n = n0 + wn + j * 16 + (lane & 15);
      float bv = (n < 512) ? bias[n] : 0.f;
#pragma unroll
      for (int r = 0; r < 4; ++r) {
        float val = acc[i][j][r] + bv;
        u32 me = (u32)(m + r);
        if (n < 512) {
          fpb[(size_t)me * 512 + n] = f2bf(val);
        } else {
          u32 bdx = me / 196u;
          u32 p = me - bdx * 196u;
          u32 g = (u32)(n - 512) >> 9;
          u32 n9 = (u32)(n - 512) & 511u;
          cnW[(((size_t)bdx * 4 + g) * 196 + p) * 512 + n9] = f2bf(val);
        }
      }
    }
  }
}

// ---------------- hproj: hp[64][2560] = h[64][512] @ wcT[2560][512]^T (f32 out) ----------------
// grid 160 (16-col tiles), 256 thr = 4 waves on K-quarters of 128.
__global__ __launch_bounds__(256) void hproj(const u16* __restrict__ hprev,
                                             const u16* __restrict__ wcT,
                                             float* __restrict__ hp) {
  const int ntile = blockIdx.x;
  const int tid = threadIdx.x, lane = tid & 63, kh = tid >> 6;
  const int l15 = lane & 15;
  const u16* Bp = wcT + (size_t)(ntile * 16 + l15) * 512 + kh * 128 + ((lane >> 4) * 8);
  const u16* Ap = hprev + (size_t)l15 * 512 + kh * 128 + ((lane >> 4) * 8);
  f32x4 acc[4] = {};
#pragma unroll
  for (int ks = 0; ks < 4; ++ks) {
    bf16x8 bb = *(const bf16x8*)(Bp + ks * 32);
#pragma unroll
    for (int mf = 0; mf < 4; ++mf) {
      bf16x8 a = *(const bf16x8*)(Ap + (size_t)mf * 16 * 512 + ks * 32);
      acc[mf] = __builtin_amdgcn_mfma_f32_16x16x32_bf16(a, bb, acc[mf], 0, 0, 0);
    }
  }
  __shared__ float pre[4][64][16];
  const int rrow = (lane >> 4) * 4;
#pragma unroll
  for (int mf = 0; mf < 4; ++mf)
#pragma unroll
    for (int r = 0; r < 4; ++r) pre[kh][mf * 16 + rrow + r][l15] = acc[mf][r];
  __syncthreads();
  const int m = tid >> 2, n = (tid & 3) * 4;
  float4 s;
  float* sp = (float*)&s;
#pragma unroll
  for (int j = 0; j < 4; ++j)
    sp[j] = pre[0][m][n + j] + pre[1][m][n + j] + pre[2][m][n + j] + pre[3][m][n + j];
  *(float4*)(hp + (size_t)m * 2560 + ntile * 16 + n) = s;
}

// ====== attn_gates: e + softmax + (alpha @ cnnW) + cell, one block per (b, n-half) ======
// grid 128: b = blk & 63, half = blk >> 6 (both halves of b land on same XCD: blk%8 == b%8).
__global__ __launch_bounds__(1024) void attn_gates(
    const u16* __restrict__ fpb, const float* __restrict__ hp, const float* __restrict__ v,
    const u16* __restrict__ cw, const float* __restrict__ xw, const float* __restrict__ bi,
    const float* __restrict__ bfg, const float* __restrict__ bc, const float* __restrict__ bo,
    float* __restrict__ cbuf, float* __restrict__ out, u16* __restrict__ hnext, int t) {
  const int b = blockIdx.x & 63;
  const int half = blockIdx.x >> 6;
  const int tid = threadIdx.x;
  const int lane = tid & 63, wid = tid >> 6;
  __shared__ float smem_a[1024];  // [0..511] hwa, [512..1023] vv; later pre4[4][256]
  __shared__ float sm[16];
  __shared__ float alp[200];
  __shared__ float red[8192];  // e[] in [0..255] first, then partials [4][8][32][8]

  float* hwa = smem_a;
  float* vv = smem_a + 512;
  if (tid < 512) {
    hwa[tid] = (t > 0) ? hp[(size_t)b * 2560 + 2048 + tid] : 0.f;
    vv[tid] = v[tid];
  }
  if (tid >= 196 && tid < 256) red[tid] = -3e38f;
  __syncthreads();

  // ---- e[p] = sum_a tanh(fp + hwa) * v ----
  float hw[8], vr[8];
#pragma unroll
  for (int j = 0; j < 8; ++j) {
    hw[j] = hwa[lane * 8 + j];
    vr[j] = vv[lane * 8 + j];
  }
  for (int p = wid; p < NP; p += 16) {
    const u16* fp = fpb + ((size_t)b * NP + p) * 512 + lane * 8;
    uint4 raw = *(const uint4*)fp;
    u32 w[4] = {raw.x, raw.y, raw.z, raw.w};
    float part = 0.f;
#pragma unroll
    for (int j = 0; j < 8; ++j) {
      u16 u = (u16)(w[j >> 1] >> ((j & 1) * 16));
      part += tanh_fast(bf2f(u) + hw[j]) * vr[j];
    }
#pragma unroll
    for (int off = 32; off > 0; off >>= 1) part += __shfl_xor(part, off);
    if (lane == 0) red[p] = part;
  }
  __syncthreads();

  // ---- softmax over 196: wave-level reduce (4 waves hold the 256 padded e-values) ----
  float ev = 0.f, w = 0.f;
  if (tid < 256) {
    ev = red[tid];
    float m_ = ev;
#pragma unroll
    for (int off = 32; off > 0; off >>= 1) m_ = fmaxf(m_, __shfl_xor(m_, off));
    if (lane == 0) sm[wid] = m_;
  }
  __syncthreads();
  if (tid < 256) {
    float mx = fmaxf(fmaxf(sm[0], sm[1]), fmaxf(sm[2], sm[3]));
    w = (tid < NP) ? __builtin_amdgcn_exp2f((ev - mx) * 1.44269504f) : 0.f;
    float s_ = w;
#pragma unroll
    for (int off = 32; off > 0; off >>= 1) s_ += __shfl_xor(s_, off);
    if (lane == 0) sm[8 + wid] = s_;
  }
  __syncthreads();
  if (tid < NP) {
    float tot = (sm[8] + sm[9]) + (sm[10] + sm[11]);
    alp[tid] = w * __builtin_amdgcn_rcpf(tot);
  }
  __syncthreads();

  // ---- gate pre-activation: pre[g][n'] = sum_p alpha[p] * cnnW[b][g][p][half*256+n'] ----
  // 1024 thr = g(4) x pg(8) x colc(32), 8 cols each via uint4.
  {
    const int g = tid >> 8, pg = (tid >> 5) & 7, colc = tid & 31;
    const u16* base = cw + ((size_t)(b * 4 + g) * 196) * 512 + half * 256 + colc * 8;
    float acc[8] = {};
    for (int i = 0; i < 25; ++i) {
      int p = pg + i * 8;
      if (p < NP) {
        float al = alp[p];
        uint4 raw = *(const uint4*)(base + (size_t)p * 512);
        u32 wds[4] = {raw.x, raw.y, raw.z, raw.w};
#pragma unroll
        for (int j = 0; j < 8; ++j) acc[j] += al * bf2f((u16)(wds[j >> 1] >> ((j & 1) * 16)));
      }
    }
#pragma unroll
    for (int j = 0; j < 8; ++j) red[((g * 8 + pg) * 32 + colc) * 8 + j] = acc[j];
  }
  __syncthreads();

  // reduce over pg into pre4 (aliases smem_a; hw/vr already in regs)
  float* pre4 = smem_a;
  {
    const int g = tid >> 8, nn = tid & 255;
    float s = 0.f;
#pragma unroll
    for (int pg = 0; pg < 8; ++pg) s += red[((g * 8 + pg) * 32 + (nn >> 3)) * 8 + (nn & 7)];
    pre4[g * 256 + nn] = s;
  }
  __syncthreads();

  // ---- LSTM cell for this half's 256 columns ----
  if (tid < 256) {
    const int ng = half * 256 + tid;
    const size_t xwo = ((size_t)t * NB + b) * 2048;
    const size_t hpb = (size_t)b * 2560;
    float hwh0 = 0.f, hwh1 = 0.f, hwh2 = 0.f, hwh3 = 0.f;
    if (t > 0) {
      hwh0 = hp[hpb + ng];
      hwh1 = hp[hpb + 512 + ng];
      hwh2 = hp[hpb + 1024 + ng];
      hwh3 = hp[hpb + 1536 + ng];
    }
    float ip = pre4[0 * 256 + tid] + xw[xwo + ng] + hwh0 + bi[ng];
    float fp = pre4[1 * 256 + tid] + xw[xwo + 512 + ng] + hwh1 + bfg[ng];
    float cp = pre4[2 * 256 + tid] + xw[xwo + 1024 + ng] + hwh2 + bc[ng];
    float op = pre4[3 * 256 + tid] + xw[xwo + 1536 + ng] + hwh3 + bo[ng];
    float it = sigmoid_fast(ip), ft = sigmoid_fast(fp), ot = sigmoid_fast(op);
    float ctl = tanh_fast(cp);
    float cold = (t > 0) ? cbuf[(size_t)b * 512 + ng] : 0.f;
    float cn = ft * cold + it * ctl;
    float hn = ot * tanh_fast(cn);
    cbuf[(size_t)b * 512 + ng] = cn;
    hnext[(size_t)b * 512 + ng] = f2bf(hn);
    out[((size_t)b * NT + t) * 512 + ng] = hn;
    if (t == NT - 1) {
      out[(size_t)NB * NT * 512 + (size_t)b * 512 + ng] = hn;
      out[(size_t)NB * NT * 512 + (size_t)NB * 512 + (size_t)b * 512 + ng] = cn;
    }
  }
}

// ======================= host launcher =======================
extern "C" void kernel_launch(void* const* d_in, const int* in_sizes, int n_in, void* d_out,
                              int out_size, void* d_ws, size_t ws_size, hipStream_t stream) {
  const float* x = (const float*)d_in[0];
  const float* cnn = (const float*)d_in[1];
  const float* Wi = (const float*)d_in[2];
  const float* bi = (const float*)d_in[3];
  const float* Wf = (const float*)d_in[4];
  const float* bfv = (const float*)d_in[5];
  const float* Wc = (const float*)d_in[6];
  const float* bc = (const float*)d_in[7];
  const float* Wo = (const float*)d_in[8];
  const float* bo = (const float*)d_in[9];
  const float* Waf = (const float*)d_in[10];
  const float* Wah = (const float*)d_in[11];
  const float* ba = (const float*)d_in[12];
  const float* v = (const float*)d_in[13];
  float* out = (float*)d_out;

  char* base = (char*)d_ws;
  size_t off = 0;
  auto alloc = [&](size_t bytes) {
    char* r = base + off;
    off += (bytes + 255) & ~(size_t)255;
    return r;
  };
  u16* cnnb = (u16*)alloc((size_t)NB * NP * NE * 2);      // 51.4 MB
  u16* fpb = (u16*)alloc((size_t)NB * NP * NA * 2);       // 12.8 MB
  u16* cnW = (u16*)alloc((size_t)NB * 4 * NP * 512 * 2);  // 51.4 MB [b][g][p][n']
  u16* wbig = (u16*)alloc((size_t)2560 * 2048 * 2);       // 10.5 MB [512 Wa_feat^T | 2048 Wctx^T]
  u16* wcombT = (u16*)alloc((size_t)2560 * 512 * 2);      // 2.6 MB  [2048 hWh | 512 hWa][512]
  u16* wxt = (u16*)alloc((size_t)4 * 512 * 512 * 2);      // 2 MB
  u16* xbT = (u16*)alloc((size_t)NT * NB * 512 * 2);      // 1.3 MB  [t][b][512]
  float* xw = (float*)alloc((size_t)NT * NB * 2048 * 4);  // 10.5 MB [t][b][2048]
  u16* hbuf = (u16*)alloc((size_t)2 * NB * 512 * 2);      // 128 KB (double buffer)
  float* cbuf = (float*)alloc((size_t)NB * 512 * 4);      // 128 KB
  float* hp = (float*)alloc((size_t)NB * 2560 * 4);       // 656 KB [b][hWh 2048 | hWa 512]

  (void)ws_size;
  (void)in_sizes;
  (void)n_in;
  (void)out_size;

  // conversions / transposes
  conv_bf16<<<2048, 256, 0, stream>>>((const float4*)cnn, cnnb, (NB * NP * NE) / 4);
  conv_x<<<dim3(NB, NT), 128, 0, stream>>>(x, xbT);
  {
    dim3 g1(512 / 32, 16, 4);   // wxt: x-part rows 0..511
    transpose_w<<<g1, 256, 0, stream>>>(Wi, Wf, Wc, Wo, wxt, 0, 512);
    dim3 g2(2048 / 32, 16, 1);  // wbig rows 0..511: Wa_feat^T
    transpose_w<<<g2, 256, 0, stream>>>(Waf, Waf, Waf, Waf, wbig, 0, 2048);
    dim3 g3(2048 / 32, 16, 4);  // wbig rows 512..2559: ctx-part of W (rows 1024..3071)
    transpose_w<<<g3, 256, 0, stream>>>(Wi, Wf, Wc, Wo, wbig + (size_t)512 * 2048, 1024, 2048);
    dim3 g4(512 / 32, 16, 4);   // wcombT[0..2047]: h-part rows 512..1023
    transpose_w<<<g4, 256, 0, stream>>>(Wi, Wf, Wc, Wo, wcombT, 512, 512);
    dim3 g5(512 / 32, 16, 1);   // wcombT[2048..2559]: Wa_h
    transpose_w<<<g5, 256, 0, stream>>>(Wah, Wah, Wah, Wah, wcombT + (size_t)2048 * 512, 0, 512);
  }

  // merged: [fpb | cnW] = cnnb @ [Wa_feat^T | Wctx^T]  (M=12544, N=2560, K=2048), 256^2 tiles
  gemm256<<<49 * 10, 512, 0, stream>>>(cnnb, wbig, ba, fpb, cnW, 2048, 10);

  // xw = xT @ W[:512,:] (4 gates) -> f32 [t*64+b][2048]
  {
    dim3 g(1280 / 128, 2048 / 128);
    gemm_bf16<<<g, 256, 0, stream>>>(xbT, wxt, xw, 1280, 2048, 512);
  }

  // 20-step recurrence: hproj (t>0) + fused attn/gates
  for (int t = 0; t < NT; ++t) {
    const u16* hprev = hbuf + (size_t)(t & 1) * NB * 512;
    u16* hnext = hbuf + (size_t)((t + 1) & 1) * NB * 512;
    if (t > 0) hproj<<<160, 256, 0, stream>>>(hprev, wcombT, hp);
    attn_gates<<<128, 1024, 0, stream>>>(fpb, hp, v, cnW, xw, bi, bfv, bc, bo, cbuf, out, hnext,
                                         t);
  }
}

// Round 9
// 694.344 us; speedup vs baseline: 2.2961x; 1.0176x over previous
//
#include <hip/hip_runtime.h>

typedef unsigned short u16;
typedef unsigned int u32;
typedef __attribute__((ext_vector_type(8))) short bf16x8;
typedef __attribute__((ext_vector_type(4))) float f32x4;

// B=64 T=20 D_IN=512 H=512 D_ENC=2048 P=196 D_ATT=512
#define NB 64
#define NT 20
#define NH 512
#define NP 196
#define NE 2048
#define NA 512

__device__ __forceinline__ u16 f2bf(float f) {
  u32 b = __float_as_uint(f);
  return (u16)((b + 0x7FFFu + ((b >> 16) & 1u)) >> 16);
}
__device__ __forceinline__ float bf2f(u16 u) { return __uint_as_float(((u32)u) << 16); }
__device__ __forceinline__ float tanh_fast(float x) {
  float xc = fminf(fmaxf(x, -15.f), 15.f);
  float e2 = __builtin_amdgcn_exp2f(xc * 2.885390082f);
  return (e2 - 1.f) * __builtin_amdgcn_rcpf(e2 + 1.f);
}
__device__ __forceinline__ float sigmoid_fast(float x) {
  return __builtin_amdgcn_rcpf(1.f + __builtin_amdgcn_exp2f(x * -1.44269504f));
}

__device__ __forceinline__ void gload_lds16(const u16* g, u16* l) {
  __builtin_amdgcn_global_load_lds((const __attribute__((address_space(1))) void*)g,
                                   (__attribute__((address_space(3))) void*)l, 16, 0, 0);
}

template <int N>
__device__ __forceinline__ void vwait() {
  if constexpr (N >= 0)
    asm volatile("s_waitcnt vmcnt(%0)" ::"i"(N) : "memory");
  else
    asm volatile("" ::: "memory");
}

// ---------------- f32 -> bf16 convert (vectorized, grid-stride) ----------------
__global__ __launch_bounds__(256) void conv_bf16(const float4* __restrict__ src,
                                                 u16* __restrict__ dst, int n4) {
  int i = blockIdx.x * 256 + threadIdx.x;
  int stride = gridDim.x * 256;
  for (; i < n4; i += stride) {
    float4 v = src[i];
    u32 lo = (u32)f2bf(v.x) | ((u32)f2bf(v.y) << 16);
    u32 hi = (u32)f2bf(v.z) | ((u32)f2bf(v.w) << 16);
    *(uint2*)(dst + (size_t)i * 4) = make_uint2(lo, hi);
  }
}

// ---------------- x [b][t][512] f32 -> xbT [t][b][512] bf16 ----------------
__global__ __launch_bounds__(128) void conv_x(const float* __restrict__ x,
                                              u16* __restrict__ xbT) {
  int b = blockIdx.x, t = blockIdx.y, tid = threadIdx.x;
  float4 v = *(const float4*)(x + ((size_t)b * NT + t) * 512 + tid * 4);
  u32 lo = (u32)f2bf(v.x) | ((u32)f2bf(v.y) << 16);
  u32 hi = (u32)f2bf(v.z) | ((u32)f2bf(v.w) << 16);
  *(uint2*)(xbT + ((size_t)t * NB + b) * 512 + tid * 4) = make_uint2(lo, hi);
}

// ------------- transpose f32 [K][512] (+row offset) -> bf16 [z*512+n][K] -------------
__global__ __launch_bounds__(256) void transpose_w(const float* __restrict__ W0,
                                                   const float* __restrict__ W1,
                                                   const float* __restrict__ W2,
                                                   const float* __restrict__ W3,
                                                   u16* __restrict__ dst, int row_off, int K) {
  const float* src = blockIdx.z == 0 ? W0 : blockIdx.z == 1 ? W1 : blockIdx.z == 2 ? W2 : W3;
  __shared__ float tile[32][33];
  int k0 = blockIdx.x * 32, n0 = blockIdx.y * 32;
  int tx = threadIdx.x & 31, ty = threadIdx.x >> 5;  // 32 x 8
#pragma unroll
  for (int i = 0; i < 4; ++i)
    tile[ty + i * 8][tx] = src[(size_t)(row_off + k0 + ty + i * 8) * 512 + n0 + tx];
  __syncthreads();
#pragma unroll
  for (int i = 0; i < 4; ++i) {
    int n = n0 + ty + i * 8, k = k0 + tx;
    dst[((size_t)blockIdx.z * 512 + n) * K + k] = f2bf(tile[tx][ty + i * 8]);
  }
}

// ------------- 128^2 bf16 MFMA GEMM (global_load_lds staging), f32 out: xw -------------
__global__ __launch_bounds__(256) void gemm_bf16(const u16* __restrict__ A,
                                                 const u16* __restrict__ BT,
                                                 float* __restrict__ C, int M, int N, int K) {
  __shared__ u16 lA[128 * 64];
  __shared__ u16 lB[128 * 64];
  const int tid = threadIdx.x;
  const int lane = tid & 63;
  const int wid = tid >> 6;
  const int m0 = blockIdx.x * 128, n0 = blockIdx.y * 128;
  const int wm = (wid >> 1) * 64, wn = (wid & 1) * 64;
  f32x4 acc[4][4] = {};

  const int cbase = wid * 256;  // wave-uniform
  int srcr[4], srcc[4];
#pragma unroll
  for (int it = 0; it < 4; ++it) {
    int c = cbase + it * 64 + lane;
    srcr[it] = c >> 3;
    srcc[it] = ((c & 7) ^ ((c >> 3) & 7)) * 8;
  }

  for (int k0 = 0; k0 < K; k0 += 64) {
    __syncthreads();
#pragma unroll
    for (int it = 0; it < 4; ++it) {
      gload_lds16(A + (size_t)(m0 + srcr[it]) * K + k0 + srcc[it],
                  lA + (size_t)(cbase + it * 64) * 8);
      gload_lds16(BT + (size_t)(n0 + srcr[it]) * K + k0 + srcc[it],
                  lB + (size_t)(cbase + it * 64) * 8);
    }
    __syncthreads();
#pragma unroll
    for (int kk = 0; kk < 2; ++kk) {
      int kchunk = kk * 4 + (lane >> 4);
      bf16x8 af[4], bg[4];
#pragma unroll
      for (int i = 0; i < 4; ++i) {
        int row = wm + i * 16 + (lane & 15);
        af[i] = *(const bf16x8*)(lA + row * 64 + ((kchunk ^ (row & 7)) * 8));
        int rowb = wn + i * 16 + (lane & 15);
        bg[i] = *(const bf16x8*)(lB + rowb * 64 + ((kchunk ^ (rowb & 7)) * 8));
      }
#pragma unroll
      for (int i = 0; i < 4; ++i)
#pragma unroll
        for (int j = 0; j < 4; ++j)
          acc[i][j] = __builtin_amdgcn_mfma_f32_16x16x32_bf16(af[i], bg[j], acc[i][j], 0, 0, 0);
    }
  }
#pragma unroll
  for (int i = 0; i < 4; ++i) {
    int m = m0 + wm + i * 16 + ((lane >> 4) * 4);
#pragma unroll
    for (int j = 0; j < 4; ++j) {
      int n = n0 + wn + j * 16 + (lane & 15);
#pragma unroll
      for (int r = 0; r < 4; ++r) C[(size_t)(m + r) * N + n] = acc[i][j][r];
    }
  }
}

// ------- 256^2 bf16 MFMA GEMM, 8-phase counted-vmcnt schedule (T3+T4+T5+T2) -------
// 512 thr = 8 waves. Wave frags: m-frag i -> row (i>>2)*128 + (wid>>2)*64 + (i&3)*16,
// n-frag j -> col (j>>1)*128 + (wid&3)*32 + (j&1)*16  => phase (mh,nh) touches only
// A-half mh / B-half nh. Per phase: 12 ds_read ; 2 gload_lds ; vmcnt(N) ; s_barrier ;
// setprio(1) ; 16 MFMA ; setprio(0) ; s_barrier. Stage order A0,B0,A1,B1 per K-tile.
// Epilogue: n<512 -> fpb(+ba), n>=512 -> cnW remap.
#define PHASE(MH, NH, CUR, DOSTAGE, MATB, HH, K1, WN)                                     \
  do {                                                                                    \
    const u16* pA_ = lds + (CUR) * 32768;                                                 \
    const u16* pB_ = pA_ + 16384;                                                         \
    bf16x8 af_[2][4], bg_[2][2];                                                          \
    _Pragma("unroll") for (int kh_ = 0; kh_ < 2; ++kh_) {                                 \
      const int kc_ = kh_ * 4 + (lane >> 4);                                              \
      _Pragma("unroll") for (int i_ = 0; i_ < 4; ++i_) {                                  \
        const int rw_ = (MH) * 128 + wmB + i_ * 16 + l15;                                 \
        af_[kh_][i_] = *(const bf16x8*)(pA_ + rw_ * 64 + ((kc_ ^ (rw_ & 7)) * 8));        \
      }                                                                                   \
      _Pragma("unroll") for (int j_ = 0; j_ < 2; ++j_) {                                  \
        const int rw_ = (NH) * 128 + wnB + j_ * 16 + l15;                                 \
        bg_[kh_][j_] = *(const bf16x8*)(pB_ + rw_ * 64 + ((kc_ ^ (rw_ & 7)) * 8));        \
      }                                                                                   \
    }                                                                                     \
    if (DOSTAGE) {                                                                        \
      const u16* gsrc_ = (MATB) ? BT : A;                                                 \
      const int r0_ = (MATB) ? n0 : m0;                                                   \
      u16* ldst_ = lds + (1 - (CUR)) * 32768 + (MATB) * 16384;                            \
      _Pragma("unroll") for (int s_ = 0; s_ < 2; ++s_)                                    \
          gload_lds16(gsrc_ + (size_t)(r0_ + srcR[HH][s_]) * K + (K1) + srcC[HH][s_],     \
                      ldst_ + ldsOff[HH][s_]);                                            \
    }                                                                                     \
    vwait<WN>();                                                                          \
    __builtin_amdgcn_s_barrier();                                                         \
    __builtin_amdgcn_s_setprio(1);                                                        \
    _Pragma("unroll") for (int kh_ = 0; kh_ < 2; ++kh_)                                   \
      _Pragma("unroll") for (int i_ = 0; i_ < 4; ++i_)                                    \
        _Pragma("unroll") for (int j_ = 0; j_ < 2; ++j_)                                  \
          acc[(MH) * 4 + i_][(NH) * 2 + j_] = __builtin_amdgcn_mfma_f32_16x16x32_bf16(    \
              af_[kh_][i_], bg_[kh_][j_], acc[(MH) * 4 + i_][(NH) * 2 + j_], 0, 0, 0);    \
    __builtin_amdgcn_s_setprio(0);                                                        \
    __builtin_amdgcn_s_barrier();                                                         \
  } while (0)

__global__ __launch_bounds__(512, 2) void gemm256(const u16* __restrict__ A,
                                                  const u16* __restrict__ BT,
                                                  const float* __restrict__ bias,
                                                  u16* __restrict__ fpb, u16* __restrict__ cnW,
                                                  int K, int grid_n) {
  __shared__ u16 lds[65536];  // [buf][A 16384 | B 16384] u16 = 128 KiB
  const int tid = threadIdx.x;
  const int lane = tid & 63;
  const int wid = tid >> 6;
  const int l15 = lane & 15;
  // bijective XCD-chunked swizzle (m204)
  const int nblk = gridDim.x;
  const int q = nblk >> 3, rr = nblk & 7;
  const int xcd = blockIdx.x & 7, jj = blockIdx.x >> 3;
  const int swz = (xcd < rr ? xcd * (q + 1) : rr * (q + 1) + (xcd - rr) * q) + jj;
  const int mt = swz / grid_n, nt = swz - mt * grid_n;
  const int m0 = mt * 256, n0 = nt * 256;
  const int wmB = (wid >> 2) * 64;  // within-half m base
  const int wnB = (wid & 3) * 32;   // within-half n base
  f32x4 acc[8][4] = {};

  // staging geometry: half-tile h (128 rows) = chunks [h*1024, h*1024+1024); 2 chunks/thread.
  int srcR[2][2], srcC[2][2], ldsOff[2][2];
#pragma unroll
  for (int h = 0; h < 2; ++h)
#pragma unroll
    for (int s = 0; s < 2; ++s) {
      int c = h * 1024 + s * 512 + wid * 64 + lane;
      srcR[h][s] = c >> 3;
      srcC[h][s] = ((c & 7) ^ ((c >> 3) & 7)) * 8;
      ldsOff[h][s] = (h * 1024 + s * 512 + wid * 64) * 8;  // wave-uniform (+lane*16B by HW)
    }

  // prologue: stage k-tile 0 (order A0, B0, A1, B1), validate A0+B0
#pragma unroll
  for (int s = 0; s < 2; ++s)
    gload_lds16(A + (size_t)(m0 + srcR[0][s]) * K + srcC[0][s], lds + ldsOff[0][s]);
#pragma unroll
  for (int s = 0; s < 2; ++s)
    gload_lds16(BT + (size_t)(n0 + srcR[0][s]) * K + srcC[0][s], lds + 16384 + ldsOff[0][s]);
#pragma unroll
  for (int s = 0; s < 2; ++s)
    gload_lds16(A + (size_t)(m0 + srcR[1][s]) * K + srcC[1][s], lds + ldsOff[1][s]);
#pragma unroll
  for (int s = 0; s < 2; ++s)
    gload_lds16(BT + (size_t)(n0 + srcR[1][s]) * K + srcC[1][s], lds + 16384 + ldsOff[1][s]);
  vwait<4>();
  __builtin_amdgcn_s_barrier();

  const int KT = K >> 6;
  for (int kt = 0; kt < KT - 1; ++kt) {
    const int cur = kt & 1;
    const int k1 = (kt + 1) << 6;
    PHASE(0, 0, cur, 1, 0, 0, k1, 4);   // read A0,B0 ; stage A0' ; next needs A1
    PHASE(1, 0, cur, 1, 1, 0, k1, 4);   // read A1,B0 ; stage B0' ; next needs B1
    PHASE(0, 1, cur, 1, 0, 1, k1, -1);  // read A0,B1 ; stage A1' ; next already valid
    PHASE(1, 1, cur, 1, 1, 1, k1, 4);   // read A1,B1 ; stage B1' ; next tile needs A0',B0'
  }
  {
    const int cur = (KT - 1) & 1;  // peeled last tile: no staging; drain progressively
    PHASE(0, 0, cur, 0, 0, 0, 0, 2);
    PHASE(1, 0, cur, 0, 0, 0, 0, 0);
    PHASE(0, 1, cur, 0, 0, 0, 0, -1);
    PHASE(1, 1, cur, 0, 0, 0, 0, -1);
  }

#pragma unroll
  for (int i = 0; i < 8; ++i) {
    int m = m0 + (i >> 2) * 128 + wmB + (i & 3) * 16 + ((lane >> 4) * 4);
#pragma unroll
    for (int j = 0; j < 4; ++j) {
      int n = n0 + (j >> 1) * 128 + wnB + (j & 1) * 16 + l15;
      float bv = (n < 512) ? bias[n] : 0.f;
#pragma unroll
      for (int r = 0; r < 4; ++r) {
        float val = acc[i][j][r] + bv;
        u32 me = (u32)(m + r);
        if (n < 512) {
          fpb[(size_t)me * 512 + n] = f2bf(val);
        } else {
          u32 bdx = me / 196u;
          u32 p = me - bdx * 196u;
          u32 g = (u32)(n - 512) >> 9;
          u32 n9 = (u32)(n - 512) & 511u;
          cnW[(((size_t)bdx * 4 + g) * 196 + p) * 512 + n9] = f2bf(val);
        }
      }
    }
  }
}

// ---------------- hproj: hp[64][2560] = h[64][512] @ wcT[2560][512]^T (f32 out) ----------------
// grid 160 (16-col tiles), 256 thr = 4 waves on K-quarters of 128.
__global__ __launch_bounds__(256) void hproj(const u16* __restrict__ hprev,
                                             const u16* __restrict__ wcT,
                                             float* __restrict__ hp) {
  const int ntile = blockIdx.x;
  const int tid = threadIdx.x, lane = tid & 63, kh = tid >> 6;
  const int l15 = lane & 15;
  const u16* Bp = wcT + (size_t)(ntile * 16 + l15) * 512 + kh * 128 + ((lane >> 4) * 8);
  const u16* Ap = hprev + (size_t)l15 * 512 + kh * 128 + ((lane >> 4) * 8);
  f32x4 acc[4] = {};
#pragma unroll
  for (int ks = 0; ks < 4; ++ks) {
    bf16x8 bb = *(const bf16x8*)(Bp + ks * 32);
#pragma unroll
    for (int mf = 0; mf < 4; ++mf) {
      bf16x8 a = *(const bf16x8*)(Ap + (size_t)mf * 16 * 512 + ks * 32);
      acc[mf] = __builtin_amdgcn_mfma_f32_16x16x32_bf16(a, bb, acc[mf], 0, 0, 0);
    }
  }
  __shared__ float pre[4][64][16];
  const int rrow = (lane >> 4) * 4;
#pragma unroll
  for (int mf = 0; mf < 4; ++mf)
#pragma unroll
    for (int r = 0; r < 4; ++r) pre[kh][mf * 16 + rrow + r][l15] = acc[mf][r];
  __syncthreads();
  const int m = tid >> 2, n = (tid & 3) * 4;
  float4 s;
  float* sp = (float*)&s;
#pragma unroll
  for (int j = 0; j < 4; ++j)
    sp[j] = pre[0][m][n + j] + pre[1][m][n + j] + pre[2][m][n + j] + pre[3][m][n + j];
  *(float4*)(hp + (size_t)m * 2560 + ntile * 16 + n) = s;
}

// ====== attn_gates: e + softmax + (alpha @ cnnW) + cell, one block per (b, n-half) ======
// grid 128: b = blk & 63, half = blk >> 6 (both halves of b land on same XCD: blk%8 == b%8).
__global__ __launch_bounds__(1024) void attn_gates(
    const u16* __restrict__ fpb, const float* __restrict__ hp, const float* __restrict__ v,
    const u16* __restrict__ cw, const float* __restrict__ xw, const float* __restrict__ bi,
    const float* __restrict__ bfg, const float* __restrict__ bc, const float* __restrict__ bo,
    float* __restrict__ cbuf, float* __restrict__ out, u16* __restrict__ hnext, int t) {
  const int b = blockIdx.x & 63;
  const int half = blockIdx.x >> 6;
  const int tid = threadIdx.x;
  const int lane = tid & 63, wid = tid >> 6;
  __shared__ float smem_a[1024];  // [0..511] hwa, [512..1023] vv; later pre4[4][256]
  __shared__ float sm[16];
  __shared__ float alp[200];
  __shared__ float red[8192];  // e[] in [0..255] first, then partials [4][8][32][8]

  float* hwa = smem_a;
  float* vv = smem_a + 512;
  if (tid < 512) {
    hwa[tid] = (t > 0) ? hp[(size_t)b * 2560 + 2048 + tid] : 0.f;
    vv[tid] = v[tid];
  }
  if (tid >= 196 && tid < 256) red[tid] = -3e38f;
  __syncthreads();

  // ---- e[p] = sum_a tanh(fp + hwa) * v ----
  float hw[8], vr[8];
#pragma unroll
  for (int j = 0; j < 8; ++j) {
    hw[j] = hwa[lane * 8 + j];
    vr[j] = vv[lane * 8 + j];
  }
  for (int p = wid; p < NP; p += 16) {
    const u16* fp = fpb + ((size_t)b * NP + p) * 512 + lane * 8;
    uint4 raw = *(const uint4*)fp;
    u32 w[4] = {raw.x, raw.y, raw.z, raw.w};
    float part = 0.f;
#pragma unroll
    for (int j = 0; j < 8; ++j) {
      u16 u = (u16)(w[j >> 1] >> ((j & 1) * 16));
      part += tanh_fast(bf2f(u) + hw[j]) * vr[j];
    }
#pragma unroll
    for (int off = 32; off > 0; off >>= 1) part += __shfl_xor(part, off);
    if (lane == 0) red[p] = part;
  }
  __syncthreads();

  // ---- softmax over 196: wave-level reduce (4 waves hold the 256 padded e-values) ----
  float ev = 0.f, w = 0.f;
  if (tid < 256) {
    ev = red[tid];
    float m_ = ev;
#pragma unroll
    for (int off = 32; off > 0; off >>= 1) m_ = fmaxf(m_, __shfl_xor(m_, off));
    if (lane == 0) sm[wid] = m_;
  }
  __syncthreads();
  if (tid < 256) {
    float mx = fmaxf(fmaxf(sm[0], sm[1]), fmaxf(sm[2], sm[3]));
    w = (tid < NP) ? __builtin_amdgcn_exp2f((ev - mx) * 1.44269504f) : 0.f;
    float s_ = w;
#pragma unroll
    for (int off = 32; off > 0; off >>= 1) s_ += __shfl_xor(s_, off);
    if (lane == 0) sm[8 + wid] = s_;
  }
  __syncthreads();
  if (tid < NP) {
    float tot = (sm[8] + sm[9]) + (sm[10] + sm[11]);
    alp[tid] = w * __builtin_amdgcn_rcpf(tot);
  }
  __syncthreads();

  // ---- gate pre-activation: pre[g][n'] = sum_p alpha[p] * cnnW[b][g][p][half*256+n'] ----
  // 1024 thr = g(4) x pg(8) x colc(32), 8 cols each via uint4.
  {
    const int g = tid >> 8, pg = (tid >> 5) & 7, colc = tid & 31;
    const u16* base = cw + ((size_t)(b * 4 + g) * 196) * 512 + half * 256 + colc * 8;
    float acc[8] = {};
    for (int i = 0; i < 25; ++i) {
      int p = pg + i * 8;
      if (p < NP) {
        float al = alp[p];
        uint4 raw = *(const uint4*)(base + (size_t)p * 512);
        u32 wds[4] = {raw.x, raw.y, raw.z, raw.w};
#pragma unroll
        for (int j = 0; j < 8; ++j) acc[j] += al * bf2f((u16)(wds[j >> 1] >> ((j & 1) * 16)));
      }
    }
#pragma unroll
    for (int j = 0; j < 8; ++j) red[((g * 8 + pg) * 32 + colc) * 8 + j] = acc[j];
  }
  __syncthreads();

  // reduce over pg into pre4 (aliases smem_a; hw/vr already in regs)
  float* pre4 = smem_a;
  {
    const int g = tid >> 8, nn = tid & 255;
    float s = 0.f;
#pragma unroll
    for (int pg = 0; pg < 8; ++pg) s += red[((g * 8 + pg) * 32 + (nn >> 3)) * 8 + (nn & 7)];
    pre4[g * 256 + nn] = s;
  }
  __syncthreads();

  // ---- LSTM cell for this half's 256 columns ----
  if (tid < 256) {
    const int ng = half * 256 + tid;
    const size_t xwo = ((size_t)t * NB + b) * 2048;
    const size_t hpb = (size_t)b * 2560;
    float hwh0 = 0.f, hwh1 = 0.f, hwh2 = 0.f, hwh3 = 0.f;
    if (t > 0) {
      hwh0 = hp[hpb + ng];
      hwh1 = hp[hpb + 512 + ng];
      hwh2 = hp[hpb + 1024 + ng];
      hwh3 = hp[hpb + 1536 + ng];
    }
    float ip = pre4[0 * 256 + tid] + xw[xwo + ng] + hwh0 + bi[ng];
    float fp = pre4[1 * 256 + tid] + xw[xwo + 512 + ng] + hwh1 + bfg[ng];
    float cp = pre4[2 * 256 + tid] + xw[xwo + 1024 + ng] + hwh2 + bc[ng];
    float op = pre4[3 * 256 + tid] + xw[xwo + 1536 + ng] + hwh3 + bo[ng];
    float it = sigmoid_fast(ip), ft = sigmoid_fast(fp), ot = sigmoid_fast(op);
    float ctl = tanh_fast(cp);
    float cold = (t > 0) ? cbuf[(size_t)b * 512 + ng] : 0.f;
    float cn = ft * cold + it * ctl;
    float hn = ot * tanh_fast(cn);
    cbuf[(size_t)b * 512 + ng] = cn;
    hnext[(size_t)b * 512 + ng] = f2bf(hn);
    out[((size_t)b * NT + t) * 512 + ng] = hn;
    if (t == NT - 1) {
      out[(size_t)NB * NT * 512 + (size_t)b * 512 + ng] = hn;
      out[(size_t)NB * NT * 512 + (size_t)NB * 512 + (size_t)b * 512 + ng] = cn;
    }
  }
}

// ======================= host launcher =======================
extern "C" void kernel_launch(void* const* d_in, const int* in_sizes, int n_in, void* d_out,
                              int out_size, void* d_ws, size_t ws_size, hipStream_t stream) {
  const float* x = (const float*)d_in[0];
  const float* cnn = (const float*)d_in[1];
  const float* Wi = (const float*)d_in[2];
  const float* bi = (const float*)d_in[3];
  const float* Wf = (const float*)d_in[4];
  const float* bfv = (const float*)d_in[5];
  const float* Wc = (const float*)d_in[6];
  const float* bc = (const float*)d_in[7];
  const float* Wo = (const float*)d_in[8];
  const float* bo = (const float*)d_in[9];
  const float* Waf = (const float*)d_in[10];
  const float* Wah = (const float*)d_in[11];
  const float* ba = (const float*)d_in[12];
  const float* v = (const float*)d_in[13];
  float* out = (float*)d_out;

  char* base = (char*)d_ws;
  size_t off = 0;
  auto alloc = [&](size_t bytes) {
    char* r = base + off;
    off += (bytes + 255) & ~(size_t)255;
    return r;
  };
  u16* cnnb = (u16*)alloc((size_t)NB * NP * NE * 2);      // 51.4 MB
  u16* fpb = (u16*)alloc((size_t)NB * NP * NA * 2);       // 12.8 MB
  u16* cnW = (u16*)alloc((size_t)NB * 4 * NP * 512 * 2);  // 51.4 MB [b][g][p][n']
  u16* wbig = (u16*)alloc((size_t)2560 * 2048 * 2);       // 10.5 MB [512 Wa_feat^T | 2048 Wctx^T]
  u16* wcombT = (u16*)alloc((size_t)2560 * 512 * 2);      // 2.6 MB  [2048 hWh | 512 hWa][512]
  u16* wxt = (u16*)alloc((size_t)4 * 512 * 512 * 2);      // 2 MB
  u16* xbT = (u16*)alloc((size_t)NT * NB * 512 * 2);      // 1.3 MB  [t][b][512]
  float* xw = (float*)alloc((size_t)NT * NB * 2048 * 4);  // 10.5 MB [t][b][2048]
  u16* hbuf = (u16*)alloc((size_t)2 * NB * 512 * 2);      // 128 KB (double buffer)
  float* cbuf = (float*)alloc((size_t)NB * 512 * 4);      // 128 KB
  float* hp = (float*)alloc((size_t)NB * 2560 * 4);       // 656 KB [b][hWh 2048 | hWa 512]

  (void)ws_size;
  (void)in_sizes;
  (void)n_in;
  (void)out_size;

  // conversions / transposes
  conv_bf16<<<2048, 256, 0, stream>>>((const float4*)cnn, cnnb, (NB * NP * NE) / 4);
  conv_x<<<dim3(NB, NT), 128, 0, stream>>>(x, xbT);
  {
    dim3 g1(512 / 32, 16, 4);   // wxt: x-part rows 0..511
    transpose_w<<<g1, 256, 0, stream>>>(Wi, Wf, Wc, Wo, wxt, 0, 512);
    dim3 g2(2048 / 32, 16, 1);  // wbig rows 0..511: Wa_feat^T
    transpose_w<<<g2, 256, 0, stream>>>(Waf, Waf, Waf, Waf, wbig, 0, 2048);
    dim3 g3(2048 / 32, 16, 4);  // wbig rows 512..2559: ctx-part of W (rows 1024..3071)
    transpose_w<<<g3, 256, 0, stream>>>(Wi, Wf, Wc, Wo, wbig + (size_t)512 * 2048, 1024, 2048);
    dim3 g4(512 / 32, 16, 4);   // wcombT[0..2047]: h-part rows 512..1023
    transpose_w<<<g4, 256, 0, stream>>>(Wi, Wf, Wc, Wo, wcombT, 512, 512);
    dim3 g5(512 / 32, 16, 1);   // wcombT[2048..2559]: Wa_h
    transpose_w<<<g5, 256, 0, stream>>>(Wah, Wah, Wah, Wah, wcombT + (size_t)2048 * 512, 0, 512);
  }

  // merged: [fpb | cnW] = cnnb @ [Wa_feat^T | Wctx^T]  (M=12544, N=2560, K=2048), 8-phase 256^2
  gemm256<<<49 * 10, 512, 0, stream>>>(cnnb, wbig, ba, fpb, cnW, 2048, 10);

  // xw = xT @ W[:512,:] (4 gates) -> f32 [t*64+b][2048]
  {
    dim3 g(1280 / 128, 2048 / 128);
    gemm_bf16<<<g, 256, 0, stream>>>(xbT, wxt, xw, 1280, 2048, 512);
  }

  // 20-step recurrence: hproj (t>0) + fused attn/gates
  for (int t = 0; t < NT; ++t) {
    const u16* hprev = hbuf + (size_t)(t & 1) * NB * 512;
    u16* hnext = hbuf + (size_t)((t + 1) & 1) * NB * 512;
    if (t > 0) hproj<<<160, 256, 0, stream>>>(hprev, wcombT, hp);
    attn_gates<<<128, 1024, 0, stream>>>(fpb, hp, v, cnW, xw, bi, bfv, bc, bo, cbuf, out, hnext,
                                         t);
  }
}

// Round 10
// 675.406 us; speedup vs baseline: 2.3605x; 1.0280x over previous
//
#include <hip/hip_runtime.h>

typedef unsigned short u16;
typedef unsigned int u32;
typedef __attribute__((ext_vector_type(8))) short bf16x8;
typedef __attribute__((ext_vector_type(4))) float f32x4;

// B=64 T=20 D_IN=512 H=512 D_ENC=2048 P=196 D_ATT=512
#define NB 64
#define NT 20
#define NH 512
#define NP 196
#define NE 2048
#define NA 512

__device__ __forceinline__ u16 f2bf(float f) {
  u32 b = __float_as_uint(f);
  return (u16)((b + 0x7FFFu + ((b >> 16) & 1u)) >> 16);
}
__device__ __forceinline__ float bf2f(u16 u) { return __uint_as_float(((u32)u) << 16); }
__device__ __forceinline__ float tanh_fast(float x) {
  float xc = fminf(fmaxf(x, -15.f), 15.f);
  float e2 = __builtin_amdgcn_exp2f(xc * 2.885390082f);
  return (e2 - 1.f) * __builtin_amdgcn_rcpf(e2 + 1.f);
}
__device__ __forceinline__ float sigmoid_fast(float x) {
  return __builtin_amdgcn_rcpf(1.f + __builtin_amdgcn_exp2f(x * -1.44269504f));
}

__device__ __forceinline__ void gload_lds16(const u16* g, u16* l) {
  __builtin_amdgcn_global_load_lds((const __attribute__((address_space(1))) void*)g,
                                   (__attribute__((address_space(3))) void*)l, 16, 0, 0);
}

template <int N>
__device__ __forceinline__ void vwait() {
  if constexpr (N >= 0)
    asm volatile("s_waitcnt vmcnt(%0)" ::"i"(N) : "memory");
  else
    asm volatile("" ::: "memory");
}

// ---------------- f32 -> bf16 convert (vectorized, grid-stride) ----------------
__global__ __launch_bounds__(256) void conv_bf16(const float4* __restrict__ src,
                                                 u16* __restrict__ dst, int n4) {
  int i = blockIdx.x * 256 + threadIdx.x;
  int stride = gridDim.x * 256;
  for (; i < n4; i += stride) {
    float4 v = src[i];
    u32 lo = (u32)f2bf(v.x) | ((u32)f2bf(v.y) << 16);
    u32 hi = (u32)f2bf(v.z) | ((u32)f2bf(v.w) << 16);
    *(uint2*)(dst + (size_t)i * 4) = make_uint2(lo, hi);
  }
}

// ---------------- x [b][t][512] f32 -> xbT [t][b][512] bf16 ----------------
__global__ __launch_bounds__(128) void conv_x(const float* __restrict__ x,
                                              u16* __restrict__ xbT) {
  int b = blockIdx.x, t = blockIdx.y, tid = threadIdx.x;
  float4 v = *(const float4*)(x + ((size_t)b * NT + t) * 512 + tid * 4);
  u32 lo = (u32)f2bf(v.x) | ((u32)f2bf(v.y) << 16);
  u32 hi = (u32)f2bf(v.z) | ((u32)f2bf(v.w) << 16);
  *(uint2*)(xbT + ((size_t)t * NB + b) * 512 + tid * 4) = make_uint2(lo, hi);
}

// ------------- transpose f32 [K][512] (+row offset) -> bf16 [z*512+n][K] -------------
__global__ __launch_bounds__(256) void transpose_w(const float* __restrict__ W0,
                                                   const float* __restrict__ W1,
                                                   const float* __restrict__ W2,
                                                   const float* __restrict__ W3,
                                                   u16* __restrict__ dst, int row_off, int K) {
  const float* src = blockIdx.z == 0 ? W0 : blockIdx.z == 1 ? W1 : blockIdx.z == 2 ? W2 : W3;
  __shared__ float tile[32][33];
  int k0 = blockIdx.x * 32, n0 = blockIdx.y * 32;
  int tx = threadIdx.x & 31, ty = threadIdx.x >> 5;  // 32 x 8
#pragma unroll
  for (int i = 0; i < 4; ++i)
    tile[ty + i * 8][tx] = src[(size_t)(row_off + k0 + ty + i * 8) * 512 + n0 + tx];
  __syncthreads();
#pragma unroll
  for (int i = 0; i < 4; ++i) {
    int n = n0 + ty + i * 8, k = k0 + tx;
    dst[((size_t)blockIdx.z * 512 + n) * K + k] = f2bf(tile[tx][ty + i * 8]);
  }
}

// ------------- 128^2 bf16 MFMA GEMM (global_load_lds staging), f32 out: xw -------------
__global__ __launch_bounds__(256) void gemm_bf16(const u16* __restrict__ A,
                                                 const u16* __restrict__ BT,
                                                 float* __restrict__ C, int M, int N, int K) {
  __shared__ u16 lA[128 * 64];
  __shared__ u16 lB[128 * 64];
  const int tid = threadIdx.x;
  const int lane = tid & 63;
  const int wid = tid >> 6;
  const int m0 = blockIdx.x * 128, n0 = blockIdx.y * 128;
  const int wm = (wid >> 1) * 64, wn = (wid & 1) * 64;
  f32x4 acc[4][4] = {};

  const int cbase = wid * 256;  // wave-uniform
  int srcr[4], srcc[4];
#pragma unroll
  for (int it = 0; it < 4; ++it) {
    int c = cbase + it * 64 + lane;
    srcr[it] = c >> 3;
    srcc[it] = ((c & 7) ^ ((c >> 3) & 7)) * 8;
  }

  for (int k0 = 0; k0 < K; k0 += 64) {
    __syncthreads();
#pragma unroll
    for (int it = 0; it < 4; ++it) {
      gload_lds16(A + (size_t)(m0 + srcr[it]) * K + k0 + srcc[it],
                  lA + (size_t)(cbase + it * 64) * 8);
      gload_lds16(BT + (size_t)(n0 + srcr[it]) * K + k0 + srcc[it],
                  lB + (size_t)(cbase + it * 64) * 8);
    }
    __syncthreads();
#pragma unroll
    for (int kk = 0; kk < 2; ++kk) {
      int kchunk = kk * 4 + (lane >> 4);
      bf16x8 af[4], bg[4];
#pragma unroll
      for (int i = 0; i < 4; ++i) {
        int row = wm + i * 16 + (lane & 15);
        af[i] = *(const bf16x8*)(lA + row * 64 + ((kchunk ^ (row & 7)) * 8));
        int rowb = wn + i * 16 + (lane & 15);
        bg[i] = *(const bf16x8*)(lB + rowb * 64 + ((kchunk ^ (rowb & 7)) * 8));
      }
#pragma unroll
      for (int i = 0; i < 4; ++i)
#pragma unroll
        for (int j = 0; j < 4; ++j)
          acc[i][j] = __builtin_amdgcn_mfma_f32_16x16x32_bf16(af[i], bg[j], acc[i][j], 0, 0, 0);
    }
  }
#pragma unroll
  for (int i = 0; i < 4; ++i) {
    int m = m0 + wm + i * 16 + ((lane >> 4) * 4);
#pragma unroll
    for (int j = 0; j < 4; ++j) {
      int n = n0 + wn + j * 16 + (lane & 15);
#pragma unroll
      for (int r = 0; r < 4; ++r) C[(size_t)(m + r) * N + n] = acc[i][j][r];
    }
  }
}

// ------- 256^2 bf16 MFMA GEMM, 8-phase snake walk (operand carry across phases) -------
// Walk (0,0)->(1,0)->(1,1)->(0,1): adjacent phases share one operand half -> 32 ds_read/tile
// (was 48). Stage order A0',B0',A1',B1'; vmcnt ledger (4,4,-1,4); tail (2,0,-1,-1).
// Epilogue: n<512 -> fpb(+ba), n>=512 -> cnW remap.
#define PHASE(MH, NH, LA, LB, CUR, DOSTAGE, MATB, HH, K1, WN)                             \
  do {                                                                                    \
    const u16* pA_ = lds + (CUR) * 32768;                                                 \
    const u16* pB_ = pA_ + 16384;                                                         \
    if (LA) {                                                                             \
      _Pragma("unroll") for (int kh_ = 0; kh_ < 2; ++kh_) {                               \
        const int kc_ = kh_ * 4 + (lane >> 4);                                            \
        _Pragma("unroll") for (int i_ = 0; i_ < 4; ++i_) {                                \
          const int rw_ = (MH) * 128 + wmB + i_ * 16 + l15;                               \
          af[kh_][i_] = *(const bf16x8*)(pA_ + rw_ * 64 + ((kc_ ^ (rw_ & 7)) * 8));       \
        }                                                                                 \
      }                                                                                   \
    }                                                                                     \
    if (LB) {                                                                             \
      _Pragma("unroll") for (int kh_ = 0; kh_ < 2; ++kh_) {                               \
        const int kc_ = kh_ * 4 + (lane >> 4);                                            \
        _Pragma("unroll") for (int j_ = 0; j_ < 2; ++j_) {                                \
          const int rw_ = (NH) * 128 + wnB + j_ * 16 + l15;                               \
          bg[kh_][j_] = *(const bf16x8*)(pB_ + rw_ * 64 + ((kc_ ^ (rw_ & 7)) * 8));       \
        }                                                                                 \
      }                                                                                   \
    }                                                                                     \
    if (DOSTAGE) {                                                                        \
      const u16* gsrc_ = (MATB) ? BT : A;                                                 \
      const int r0_ = (MATB) ? n0 : m0;                                                   \
      u16* ldst_ = lds + (1 - (CUR)) * 32768 + (MATB) * 16384;                            \
      _Pragma("unroll") for (int s_ = 0; s_ < 2; ++s_)                                    \
          gload_lds16(gsrc_ + (size_t)(r0_ + srcR[HH][s_]) * K + (K1) + srcC[HH][s_],     \
                      ldst_ + ldsOff[HH][s_]);                                            \
    }                                                                                     \
    vwait<WN>();                                                                          \
    __builtin_amdgcn_s_barrier();                                                         \
    __builtin_amdgcn_s_setprio(1);                                                        \
    _Pragma("unroll") for (int kh_ = 0; kh_ < 2; ++kh_)                                   \
      _Pragma("unroll") for (int i_ = 0; i_ < 4; ++i_)                                    \
        _Pragma("unroll") for (int j_ = 0; j_ < 2; ++j_)                                  \
          acc[(MH) * 4 + i_][(NH) * 2 + j_] = __builtin_amdgcn_mfma_f32_16x16x32_bf16(    \
              af[kh_][i_], bg[kh_][j_], acc[(MH) * 4 + i_][(NH) * 2 + j_], 0, 0, 0);      \
    __builtin_amdgcn_s_setprio(0);                                                        \
    __builtin_amdgcn_s_barrier();                                                         \
  } while (0)

__global__ __launch_bounds__(512, 2) void gemm256(const u16* __restrict__ A,
                                                  const u16* __restrict__ BT,
                                                  const float* __restrict__ bias,
                                                  u16* __restrict__ fpb, u16* __restrict__ cnW,
                                                  int K, int grid_n) {
  __shared__ u16 lds[65536];  // [buf][A 16384 | B 16384] u16 = 128 KiB
  const int tid = threadIdx.x;
  const int lane = tid & 63;
  const int wid = tid >> 6;
  const int l15 = lane & 15;
  // bijective XCD-chunked swizzle (m204)
  const int nblk = gridDim.x;
  const int q = nblk >> 3, rr = nblk & 7;
  const int xcd = blockIdx.x & 7, jj = blockIdx.x >> 3;
  const int swz = (xcd < rr ? xcd * (q + 1) : rr * (q + 1) + (xcd - rr) * q) + jj;
  const int mt = swz / grid_n, nt = swz - mt * grid_n;
  const int m0 = mt * 256, n0 = nt * 256;
  const int wmB = (wid >> 2) * 64;  // within-half m base
  const int wnB = (wid & 3) * 32;   // within-half n base
  f32x4 acc[8][4] = {};
  bf16x8 af[2][4], bg[2][2];  // carried across adjacent phases

  // staging geometry: half-tile h (128 rows) = chunks [h*1024, h*1024+1024); 2 chunks/thread.
  int srcR[2][2], srcC[2][2], ldsOff[2][2];
#pragma unroll
  for (int h = 0; h < 2; ++h)
#pragma unroll
    for (int s = 0; s < 2; ++s) {
      int c = h * 1024 + s * 512 + wid * 64 + lane;
      srcR[h][s] = c >> 3;
      srcC[h][s] = ((c & 7) ^ ((c >> 3) & 7)) * 8;
      ldsOff[h][s] = (h * 1024 + s * 512 + wid * 64) * 8;  // wave-uniform (+lane*16B by HW)
    }

  // prologue: stage k-tile 0 (order A0, B0, A1, B1), validate A0+B0
#pragma unroll
  for (int s = 0; s < 2; ++s)
    gload_lds16(A + (size_t)(m0 + srcR[0][s]) * K + srcC[0][s], lds + ldsOff[0][s]);
#pragma unroll
  for (int s = 0; s < 2; ++s)
    gload_lds16(BT + (size_t)(n0 + srcR[0][s]) * K + srcC[0][s], lds + 16384 + ldsOff[0][s]);
#pragma unroll
  for (int s = 0; s < 2; ++s)
    gload_lds16(A + (size_t)(m0 + srcR[1][s]) * K + srcC[1][s], lds + ldsOff[1][s]);
#pragma unroll
  for (int s = 0; s < 2; ++s)
    gload_lds16(BT + (size_t)(n0 + srcR[1][s]) * K + srcC[1][s], lds + 16384 + ldsOff[1][s]);
  vwait<4>();
  __builtin_amdgcn_s_barrier();

  const int KT = K >> 6;
  for (int kt = 0; kt < KT - 1; ++kt) {
    const int cur = kt & 1;
    const int k1 = (kt + 1) << 6;
    PHASE(0, 0, 1, 1, cur, 1, 0, 0, k1, 4);   // load A0,B0 ; stage A0' ; validate A1
    PHASE(1, 0, 1, 0, cur, 1, 1, 0, k1, 4);   // load A1 (carry B0) ; stage B0' ; validate B1
    PHASE(1, 1, 0, 1, cur, 1, 0, 1, k1, -1);  // load B1 (carry A1) ; stage A1'
    PHASE(0, 1, 1, 0, cur, 1, 1, 1, k1, 4);   // load A0 (carry B1) ; stage B1' ; validate A0',B0'
  }
  {
    const int cur = (KT - 1) & 1;  // peeled last tile: no staging; drain progressively
    PHASE(0, 0, 1, 1, cur, 0, 0, 0, 0, 2);
    PHASE(1, 0, 1, 0, cur, 0, 0, 0, 0, 0);
    PHASE(1, 1, 0, 1, cur, 0, 0, 0, 0, -1);
    PHASE(0, 1, 1, 0, cur, 0, 0, 0, 0, -1);
  }

#pragma unroll
  for (int i = 0; i < 8; ++i) {
    int m = m0 + (i >> 2) * 128 + wmB + (i & 3) * 16 + ((lane >> 4) * 4);
#pragma unroll
    for (int j = 0; j < 4; ++j) {
      int n = n0 + (j >> 1) * 128 + wnB + (j & 1) * 16 + l15;
      float bv = (n < 512) ? bias[n] : 0.f;
#pragma unroll
      for (int r = 0; r < 4; ++r) {
        float val = acc[i][j][r] + bv;
        u32 me = (u32)(m + r);
        if (n < 512) {
          fpb[(size_t)me * 512 + n] = f2bf(val);
        } else {
          u32 bdx = me / 196u;
          u32 p = me - bdx * 196u;
          u32 g = (u32)(n - 512) >> 9;
          u32 n9 = (u32)(n - 512) & 511u;
          cnW[(((size_t)bdx * 4 + g) * 196 + p) * 512 + n9] = f2bf(val);
        }
      }
    }
  }
}

// ---------------- hproj: hp[64][2560] = h[64][512] @ wcT[2560][512]^T (f32 out) ----------------
// grid 160 (16-col tiles), 256 thr = 4 waves on K-quarters of 128.
__global__ __launch_bounds__(256) void hproj(const u16* __restrict__ hprev,
                                             const u16* __restrict__ wcT,
                                             float* __restrict__ hp) {
  const int ntile = blockIdx.x;
  const int tid = threadIdx.x, lane = tid & 63, kh = tid >> 6;
  const int l15 = lane & 15;
  const u16* Bp = wcT + (size_t)(ntile * 16 + l15) * 512 + kh * 128 + ((lane >> 4) * 8);
  const u16* Ap = hprev + (size_t)l15 * 512 + kh * 128 + ((lane >> 4) * 8);
  f32x4 acc[4] = {};
#pragma unroll
  for (int ks = 0; ks < 4; ++ks) {
    bf16x8 bb = *(const bf16x8*)(Bp + ks * 32);
#pragma unroll
    for (int mf = 0; mf < 4; ++mf) {
      bf16x8 a = *(const bf16x8*)(Ap + (size_t)mf * 16 * 512 + ks * 32);
      acc[mf] = __builtin_amdgcn_mfma_f32_16x16x32_bf16(a, bb, acc[mf], 0, 0, 0);
    }
  }
  __shared__ float pre[4][64][16];
  const int rrow = (lane >> 4) * 4;
#pragma unroll
  for (int mf = 0; mf < 4; ++mf)
#pragma unroll
    for (int r = 0; r < 4; ++r) pre[kh][mf * 16 + rrow + r][l15] = acc[mf][r];
  __syncthreads();
  const int m = tid >> 2, n = (tid & 3) * 4;
  float4 s;
  float* sp = (float*)&s;
#pragma unroll
  for (int j = 0; j < 4; ++j)
    sp[j] = pre[0][m][n + j] + pre[1][m][n + j] + pre[2][m][n + j] + pre[3][m][n + j];
  *(float4*)(hp + (size_t)m * 2560 + ntile * 16 + n) = s;
}

// ====== attn_gates: e + softmax + (alpha @ cnnW) + cell, one block per (b, n-quarter) ======
// grid 256: b = blk & 63, quarter = blk >> 6 (all 4 quarter-blocks of b share an XCD L2).
__global__ __launch_bounds__(1024) void attn_gates(
    const u16* __restrict__ fpb, const float* __restrict__ hp, const float* __restrict__ v,
    const u16* __restrict__ cw, const float* __restrict__ xw, const float* __restrict__ bi,
    const float* __restrict__ bfg, const float* __restrict__ bc, const float* __restrict__ bo,
    float* __restrict__ cbuf, float* __restrict__ out, u16* __restrict__ hnext, int t) {
  const int b = blockIdx.x & 63;
  const int quarter = blockIdx.x >> 6;  // 128 cols of [0,512)
  const int tid = threadIdx.x;
  const int lane = tid & 63, wid = tid >> 6;
  __shared__ float smem_a[1024];  // [0..511] hwa, [512..1023] vv; later pre4[4][128]
  __shared__ float sm[16];
  __shared__ float alp[200];
  __shared__ float red[8192];  // e[] in [0..255] first, then partials [4][16][16][8]

  float* hwa = smem_a;
  float* vv = smem_a + 512;
  if (tid < 512) {
    hwa[tid] = (t > 0) ? hp[(size_t)b * 2560 + 2048 + tid] : 0.f;
    vv[tid] = v[tid];
  }
  if (tid >= 196 && tid < 256) red[tid] = -3e38f;
  __syncthreads();

  // ---- e[p] = sum_a tanh(fp + hwa) * v ----
  float hw[8], vr[8];
#pragma unroll
  for (int j = 0; j < 8; ++j) {
    hw[j] = hwa[lane * 8 + j];
    vr[j] = vv[lane * 8 + j];
  }
  for (int p = wid; p < NP; p += 16) {
    const u16* fp = fpb + ((size_t)b * NP + p) * 512 + lane * 8;
    uint4 raw = *(const uint4*)fp;
    u32 w[4] = {raw.x, raw.y, raw.z, raw.w};
    float part = 0.f;
#pragma unroll
    for (int j = 0; j < 8; ++j) {
      u16 u = (u16)(w[j >> 1] >> ((j & 1) * 16));
      part += tanh_fast(bf2f(u) + hw[j]) * vr[j];
    }
#pragma unroll
    for (int off = 32; off > 0; off >>= 1) part += __shfl_xor(part, off);
    if (lane == 0) red[p] = part;
  }
  __syncthreads();

  // ---- softmax over 196: wave-level reduce (4 waves hold the 256 padded e-values) ----
  float ev = 0.f, w = 0.f;
  if (tid < 256) {
    ev = red[tid];
    float m_ = ev;
#pragma unroll
    for (int off = 32; off > 0; off >>= 1) m_ = fmaxf(m_, __shfl_xor(m_, off));
    if (lane == 0) sm[wid] = m_;
  }
  __syncthreads();
  if (tid < 256) {
    float mx = fmaxf(fmaxf(sm[0], sm[1]), fmaxf(sm[2], sm[3]));
    w = (tid < NP) ? __builtin_amdgcn_exp2f((ev - mx) * 1.44269504f) : 0.f;
    float s_ = w;
#pragma unroll
    for (int off = 32; off > 0; off >>= 1) s_ += __shfl_xor(s_, off);
    if (lane == 0) sm[8 + wid] = s_;
  }
  __syncthreads();
  if (tid < NP) {
    float tot = (sm[8] + sm[9]) + (sm[10] + sm[11]);
    alp[tid] = w * __builtin_amdgcn_rcpf(tot);
  }
  __syncthreads();

  // ---- gate pre-activation: pre[g][n'] = sum_p alpha[p]*cnnW[b][g][p][quarter*128+n'] ----
  // 1024 thr = g(4) x pg(16) x colc(16), 8 cols each via uint4.
  {
    const int g = tid >> 8, pg = (tid >> 4) & 15, colc = tid & 15;
    const u16* base = cw + ((size_t)(b * 4 + g) * 196) * 512 + quarter * 128 + colc * 8;
    float acc[8] = {};
    for (int i = 0; i < 13; ++i) {
      int p = pg + i * 16;
      if (p < NP) {
        float al = alp[p];
        uint4 raw = *(const uint4*)(base + (size_t)p * 512);
        u32 wds[4] = {raw.x, raw.y, raw.z, raw.w};
#pragma unroll
        for (int j = 0; j < 8; ++j) acc[j] += al * bf2f((u16)(wds[j >> 1] >> ((j & 1) * 16)));
      }
    }
#pragma unroll
    for (int j = 0; j < 8; ++j) red[((g * 16 + pg) * 16 + colc) * 8 + j] = acc[j];
  }
  __syncthreads();

  // reduce over pg into pre4 (aliases smem_a; hw/vr already in regs)
  float* pre4 = smem_a;
  if (tid < 512) {
    const int g = tid >> 7, nn = tid & 127;
    float s = 0.f;
#pragma unroll
    for (int pg = 0; pg < 16; ++pg) s += red[((g * 16 + pg) * 16 + (nn >> 3)) * 8 + (nn & 7)];
    pre4[g * 128 + nn] = s;
  }
  __syncthreads();

  // ---- LSTM cell for this quarter's 128 columns ----
  if (tid < 128) {
    const int ng = quarter * 128 + tid;
    const size_t xwo = ((size_t)t * NB + b) * 2048;
    const size_t hpb = (size_t)b * 2560;
    float hwh0 = 0.f, hwh1 = 0.f, hwh2 = 0.f, hwh3 = 0.f;
    if (t > 0) {
      hwh0 = hp[hpb + ng];
      hwh1 = hp[hpb + 512 + ng];
      hwh2 = hp[hpb + 1024 + ng];
      hwh3 = hp[hpb + 1536 + ng];
    }
    float ip = pre4[0 * 128 + tid] + xw[xwo + ng] + hwh0 + bi[ng];
    float fp = pre4[1 * 128 + tid] + xw[xwo + 512 + ng] + hwh1 + bfg[ng];
    float cp = pre4[2 * 128 + tid] + xw[xwo + 1024 + ng] + hwh2 + bc[ng];
    float op = pre4[3 * 128 + tid] + xw[xwo + 1536 + ng] + hwh3 + bo[ng];
    float it = sigmoid_fast(ip), ft = sigmoid_fast(fp), ot = sigmoid_fast(op);
    float ctl = tanh_fast(cp);
    float cold = (t > 0) ? cbuf[(size_t)b * 512 + ng] : 0.f;
    float cn = ft * cold + it * ctl;
    float hn = ot * tanh_fast(cn);
    cbuf[(size_t)b * 512 + ng] = cn;
    hnext[(size_t)b * 512 + ng] = f2bf(hn);
    out[((size_t)b * NT + t) * 512 + ng] = hn;
    if (t == NT - 1) {
      out[(size_t)NB * NT * 512 + (size_t)b * 512 + ng] = hn;
      out[(size_t)NB * NT * 512 + (size_t)NB * 512 + (size_t)b * 512 + ng] = cn;
    }
  }
}

// ======================= host launcher =======================
extern "C" void kernel_launch(void* const* d_in, const int* in_sizes, int n_in, void* d_out,
                              int out_size, void* d_ws, size_t ws_size, hipStream_t stream) {
  const float* x = (const float*)d_in[0];
  const float* cnn = (const float*)d_in[1];
  const float* Wi = (const float*)d_in[2];
  const float* bi = (const float*)d_in[3];
  const float* Wf = (const float*)d_in[4];
  const float* bfv = (const float*)d_in[5];
  const float* Wc = (const float*)d_in[6];
  const float* bc = (const float*)d_in[7];
  const float* Wo = (const float*)d_in[8];
  const float* bo = (const float*)d_in[9];
  const float* Waf = (const float*)d_in[10];
  const float* Wah = (const float*)d_in[11];
  const float* ba = (const float*)d_in[12];
  const float* v = (const float*)d_in[13];
  float* out = (float*)d_out;

  char* base = (char*)d_ws;
  size_t off = 0;
  auto alloc = [&](size_t bytes) {
    char* r = base + off;
    off += (bytes + 255) & ~(size_t)255;
    return r;
  };
  u16* cnnb = (u16*)alloc((size_t)NB * NP * NE * 2);      // 51.4 MB
  u16* fpb = (u16*)alloc((size_t)NB * NP * NA * 2);       // 12.8 MB
  u16* cnW = (u16*)alloc((size_t)NB * 4 * NP * 512 * 2);  // 51.4 MB [b][g][p][n']
  u16* wbig = (u16*)alloc((size_t)2560 * 2048 * 2);       // 10.5 MB [512 Wa_feat^T | 2048 Wctx^T]
  u16* wcombT = (u16*)alloc((size_t)2560 * 512 * 2);      // 2.6 MB  [2048 hWh | 512 hWa][512]
  u16* wxt = (u16*)alloc((size_t)4 * 512 * 512 * 2);      // 2 MB
  u16* xbT = (u16*)alloc((size_t)NT * NB * 512 * 2);      // 1.3 MB  [t][b][512]
  float* xw = (float*)alloc((size_t)NT * NB * 2048 * 4);  // 10.5 MB [t][b][2048]
  u16* hbuf = (u16*)alloc((size_t)2 * NB * 512 * 2);      // 128 KB (double buffer)
  float* cbuf = (float*)alloc((size_t)NB * 512 * 4);      // 128 KB
  float* hp = (float*)alloc((size_t)NB * 2560 * 4);       // 656 KB [b][hWh 2048 | hWa 512]

  (void)ws_size;
  (void)in_sizes;
  (void)n_in;
  (void)out_size;

  // conversions / transposes
  conv_bf16<<<2048, 256, 0, stream>>>((const float4*)cnn, cnnb, (NB * NP * NE) / 4);
  conv_x<<<dim3(NB, NT), 128, 0, stream>>>(x, xbT);
  {
    dim3 g1(512 / 32, 16, 4);   // wxt: x-part rows 0..511
    transpose_w<<<g1, 256, 0, stream>>>(Wi, Wf, Wc, Wo, wxt, 0, 512);
    dim3 g2(2048 / 32, 16, 1);  // wbig rows 0..511: Wa_feat^T
    transpose_w<<<g2, 256, 0, stream>>>(Waf, Waf, Waf, Waf, wbig, 0, 2048);
    dim3 g3(2048 / 32, 16, 4);  // wbig rows 512..2559: ctx-part of W (rows 1024..3071)
    transpose_w<<<g3, 256, 0, stream>>>(Wi, Wf, Wc, Wo, wbig + (size_t)512 * 2048, 1024, 2048);
    dim3 g4(512 / 32, 16, 4);   // wcombT[0..2047]: h-part rows 512..1023
    transpose_w<<<g4, 256, 0, stream>>>(Wi, Wf, Wc, Wo, wcombT, 512, 512);
    dim3 g5(512 / 32, 16, 1);   // wcombT[2048..2559]: Wa_h
    transpose_w<<<g5, 256, 0, stream>>>(Wah, Wah, Wah, Wah, wcombT + (size_t)2048 * 512, 0, 512);
  }

  // merged: [fpb | cnW] = cnnb @ [Wa_feat^T | Wctx^T]  (M=12544, N=2560, K=2048), 8-phase 256^2
  gemm256<<<49 * 10, 512, 0, stream>>>(cnnb, wbig, ba, fpb, cnW, 2048, 10);

  // xw = xT @ W[:512,:] (4 gates) -> f32 [t*64+b][2048]
  {
    dim3 g(1280 / 128, 2048 / 128);
    gemm_bf16<<<g, 256, 0, stream>>>(xbT, wxt, xw, 1280, 2048, 512);
  }

  // 20-step recurrence: hproj (t>0) + fused attn/gates
  for (int t = 0; t < NT; ++t) {
    const u16* hprev = hbuf + (size_t)(t & 1) * NB * 512;
    u16* hnext = hbuf + (size_t)((t + 1) & 1) * NB * 512;
    if (t > 0) hproj<<<160, 256, 0, stream>>>(hprev, wcombT, hp);
    attn_gates<<<256, 1024, 0, stream>>>(fpb, hp, v, cnW, xw, bi, bfv, bc, bo, cbuf, out, hnext,
                                         t);
  }
}

// Round 11
// 672.516 us; speedup vs baseline: 2.3707x; 1.0043x over previous
//
#include <hip/hip_runtime.h>

typedef unsigned short u16;
typedef unsigned int u32;
typedef __attribute__((ext_vector_type(8))) short bf16x8;
typedef __attribute__((ext_vector_type(4))) float f32x4;

// B=64 T=20 D_IN=512 H=512 D_ENC=2048 P=196 D_ATT=512
#define NB 64
#define NT 20
#define NH 512
#define NP 196
#define NE 2048
#define NA 512

__device__ __forceinline__ u16 f2bf(float f) {
  u32 b = __float_as_uint(f);
  return (u16)((b + 0x7FFFu + ((b >> 16) & 1u)) >> 16);
}
__device__ __forceinline__ float bf2f(u16 u) { return __uint_as_float(((u32)u) << 16); }
__device__ __forceinline__ float tanh_fast(float x) {
  float xc = fminf(fmaxf(x, -15.f), 15.f);
  float e2 = __builtin_amdgcn_exp2f(xc * 2.885390082f);
  return (e2 - 1.f) * __builtin_amdgcn_rcpf(e2 + 1.f);
}
__device__ __forceinline__ float sigmoid_fast(float x) {
  return __builtin_amdgcn_rcpf(1.f + __builtin_amdgcn_exp2f(x * -1.44269504f));
}

__device__ __forceinline__ void gload_lds16(const u16* g, u16* l) {
  __builtin_amdgcn_global_load_lds((const __attribute__((address_space(1))) void*)g,
                                   (__attribute__((address_space(3))) void*)l, 16, 0, 0);
}

template <int N>
__device__ __forceinline__ void vwait() {
  if constexpr (N >= 0)
    asm volatile("s_waitcnt vmcnt(%0)" ::"i"(N) : "memory");
  else
    asm volatile("" ::: "memory");
}

// ---------------- f32 -> bf16 convert (vectorized, grid-stride) ----------------
__global__ __launch_bounds__(256) void conv_bf16(const float4* __restrict__ src,
                                                 u16* __restrict__ dst, int n4) {
  int i = blockIdx.x * 256 + threadIdx.x;
  int stride = gridDim.x * 256;
  for (; i < n4; i += stride) {
    float4 v = src[i];
    u32 lo = (u32)f2bf(v.x) | ((u32)f2bf(v.y) << 16);
    u32 hi = (u32)f2bf(v.z) | ((u32)f2bf(v.w) << 16);
    *(uint2*)(dst + (size_t)i * 4) = make_uint2(lo, hi);
  }
}

// ---------------- x [b][t][512] f32 -> xbT [t][b][512] bf16 ----------------
__global__ __launch_bounds__(128) void conv_x(const float* __restrict__ x,
                                              u16* __restrict__ xbT) {
  int b = blockIdx.x, t = blockIdx.y, tid = threadIdx.x;
  float4 v = *(const float4*)(x + ((size_t)b * NT + t) * 512 + tid * 4);
  u32 lo = (u32)f2bf(v.x) | ((u32)f2bf(v.y) << 16);
  u32 hi = (u32)f2bf(v.z) | ((u32)f2bf(v.w) << 16);
  *(uint2*)(xbT + ((size_t)t * NB + b) * 512 + tid * 4) = make_uint2(lo, hi);
}

// ------------- transpose f32 [K][512] (+row offset) -> bf16 [z*512+n][K] -------------
__global__ __launch_bounds__(256) void transpose_w(const float* __restrict__ W0,
                                                   const float* __restrict__ W1,
                                                   const float* __restrict__ W2,
                                                   const float* __restrict__ W3,
                                                   u16* __restrict__ dst, int row_off, int K) {
  const float* src = blockIdx.z == 0 ? W0 : blockIdx.z == 1 ? W1 : blockIdx.z == 2 ? W2 : W3;
  __shared__ float tile[32][33];
  int k0 = blockIdx.x * 32, n0 = blockIdx.y * 32;
  int tx = threadIdx.x & 31, ty = threadIdx.x >> 5;  // 32 x 8
#pragma unroll
  for (int i = 0; i < 4; ++i)
    tile[ty + i * 8][tx] = src[(size_t)(row_off + k0 + ty + i * 8) * 512 + n0 + tx];
  __syncthreads();
#pragma unroll
  for (int i = 0; i < 4; ++i) {
    int n = n0 + ty + i * 8, k = k0 + tx;
    dst[((size_t)blockIdx.z * 512 + n) * K + k] = f2bf(tile[tx][ty + i * 8]);
  }
}

// ------------- 128^2 bf16 MFMA GEMM (global_load_lds staging), f32 out: xw -------------
__global__ __launch_bounds__(256) void gemm_bf16(const u16* __restrict__ A,
                                                 const u16* __restrict__ BT,
                                                 float* __restrict__ C, int M, int N, int K) {
  __shared__ u16 lA[128 * 64];
  __shared__ u16 lB[128 * 64];
  const int tid = threadIdx.x;
  const int lane = tid & 63;
  const int wid = tid >> 6;
  const int m0 = blockIdx.x * 128, n0 = blockIdx.y * 128;
  const int wm = (wid >> 1) * 64, wn = (wid & 1) * 64;
  f32x4 acc[4][4] = {};

  const int cbase = wid * 256;  // wave-uniform
  int srcr[4], srcc[4];
#pragma unroll
  for (int it = 0; it < 4; ++it) {
    int c = cbase + it * 64 + lane;
    srcr[it] = c >> 3;
    srcc[it] = ((c & 7) ^ ((c >> 3) & 7)) * 8;
  }

  for (int k0 = 0; k0 < K; k0 += 64) {
    __syncthreads();
#pragma unroll
    for (int it = 0; it < 4; ++it) {
      gload_lds16(A + (size_t)(m0 + srcr[it]) * K + k0 + srcc[it],
                  lA + (size_t)(cbase + it * 64) * 8);
      gload_lds16(BT + (size_t)(n0 + srcr[it]) * K + k0 + srcc[it],
                  lB + (size_t)(cbase + it * 64) * 8);
    }
    __syncthreads();
#pragma unroll
    for (int kk = 0; kk < 2; ++kk) {
      int kchunk = kk * 4 + (lane >> 4);
      bf16x8 af[4], bg[4];
#pragma unroll
      for (int i = 0; i < 4; ++i) {
        int row = wm + i * 16 + (lane & 15);
        af[i] = *(const bf16x8*)(lA + row * 64 + ((kchunk ^ (row & 7)) * 8));
        int rowb = wn + i * 16 + (lane & 15);
        bg[i] = *(const bf16x8*)(lB + rowb * 64 + ((kchunk ^ (rowb & 7)) * 8));
      }
#pragma unroll
      for (int i = 0; i < 4; ++i)
#pragma unroll
        for (int j = 0; j < 4; ++j)
          acc[i][j] = __builtin_amdgcn_mfma_f32_16x16x32_bf16(af[i], bg[j], acc[i][j], 0, 0, 0);
    }
  }
#pragma unroll
  for (int i = 0; i < 4; ++i) {
    int m = m0 + wm + i * 16 + ((lane >> 4) * 4);
#pragma unroll
    for (int j = 0; j < 4; ++j) {
      int n = n0 + wn + j * 16 + (lane & 15);
#pragma unroll
      for (int r = 0; r < 4; ++r) C[(size_t)(m + r) * N + n] = acc[i][j][r];
    }
  }
}

// ------- 256^2 bf16 MFMA GEMM, m201 wave geometry: wave owns 128x64, 24 ds_read/K-tile -------
// 512 thr = 8 waves (2 A-halves x 4 B-quarters). Per K-tile: 4 phases x 16 MFMA.
// ph0 reads all 8 B-frags (carried in regs) + A-frags 0,1; ph1-3 read A-frag pairs.
// Stage next tile front-loaded: ph0 stages A-slabs (4 loads), ph1 B-slabs (4); vmcnt(0) at ph3
// gives prefetch ~3 phases of slack. Epilogue: n<512 -> fpb(+ba), n>=512 -> cnW remap.
#define STG(SS, CUR, K1)                                                                    \
  do {                                                                                      \
    _Pragma("unroll") for (int q_ = 0; q_ < 2; ++q_) {                                      \
      const u16* g_ = ((SS) < 2)                                                            \
                          ? (A + (size_t)(m0 + sR[SS][q_]) * K + (K1) + sC[SS][q_])         \
                          : (BT + (size_t)(n0 + sR[SS][q_]) * K + (K1) + sC[SS][q_]);       \
      gload_lds16(g_, lds + ((CUR) ^ 1) * 32768 + sL[SS][q_]);                              \
    }                                                                                       \
  } while (0)

#define PH(MF0, READB, CUR, DOSTAGE, SB, K1, WN)                                            \
  do {                                                                                      \
    const u16* pA_ = lds + (CUR) * 32768;                                                   \
    const u16* pB_ = pA_ + 16384;                                                           \
    bf16x8 af_[2][2];                                                                       \
    _Pragma("unroll") for (int kh_ = 0; kh_ < 2; ++kh_) {                                   \
      const int kc_ = kh_ * 4 + (lane >> 4);                                                \
      _Pragma("unroll") for (int ii_ = 0; ii_ < 2; ++ii_) {                                 \
        const int rA_ = wmH * 128 + ((MF0) + ii_) * 16 + l15;                               \
        af_[kh_][ii_] = *(const bf16x8*)(pA_ + rA_ * 64 + ((kc_ ^ (rA_ & 7)) * 8));         \
      }                                                                                     \
      if (READB) {                                                                          \
        _Pragma("unroll") for (int j_ = 0; j_ < 4; ++j_) {                                  \
          const int rB_ = wnq * 64 + j_ * 16 + l15;                                         \
          bg[kh_][j_] = *(const bf16x8*)(pB_ + rB_ * 64 + ((kc_ ^ (rB_ & 7)) * 8));         \
        }                                                                                   \
      }                                                                                     \
    }                                                                                       \
    if (DOSTAGE) {                                                                          \
      STG(SB, CUR, K1);                                                                     \
      STG((SB) + 1, CUR, K1);                                                               \
    }                                                                                       \
    vwait<WN>();                                                                            \
    __builtin_amdgcn_s_barrier();                                                           \
    __builtin_amdgcn_s_setprio(1);                                                          \
    _Pragma("unroll") for (int kh_ = 0; kh_ < 2; ++kh_)                                     \
      _Pragma("unroll") for (int ii_ = 0; ii_ < 2; ++ii_)                                   \
        _Pragma("unroll") for (int j_ = 0; j_ < 4; ++j_)                                    \
          acc[(MF0) + ii_][j_] = __builtin_amdgcn_mfma_f32_16x16x32_bf16(                   \
              af_[kh_][ii_], bg[kh_][j_], acc[(MF0) + ii_][j_], 0, 0, 0);                   \
    __builtin_amdgcn_s_setprio(0);                                                          \
    __builtin_amdgcn_s_barrier();                                                           \
  } while (0)

__global__ __launch_bounds__(512, 2) void gemm256(const u16* __restrict__ A,
                                                  const u16* __restrict__ BT,
                                                  const float* __restrict__ bias,
                                                  u16* __restrict__ fpb, u16* __restrict__ cnW,
                                                  int K, int grid_n) {
  __shared__ u16 lds[65536];  // [buf][A 256x64 | B 256x64] u16 = 128 KiB
  const int tid = threadIdx.x;
  const int lane = tid & 63;
  const int wid = tid >> 6;
  const int l15 = lane & 15;
  // bijective XCD-chunked swizzle (m204)
  const int nblk = gridDim.x;
  const int q = nblk >> 3, rr = nblk & 7;
  const int xcd = blockIdx.x & 7, jj = blockIdx.x >> 3;
  const int swz = (xcd < rr ? xcd * (q + 1) : rr * (q + 1) + (xcd - rr) * q) + jj;
  const int mt = swz / grid_n, nt = swz - mt * grid_n;
  const int m0 = mt * 256, n0 = nt * 256;
  const int wmH = wid >> 2;  // A-half (0/1): rows wmH*128..+128
  const int wnq = wid & 3;   // B quarter: cols wnq*64..+64
  f32x4 acc[8][4] = {};
  bf16x8 bg[2][4];  // B-frags read once per K-tile (ph0), carried through ph1-3

  // staging geometry: slab s (1024 chunks of 16B): 0,1 = A rows 0-127 / 128-255;
  // 2,3 = B rows 0-127 / 128-255. Each slab = 2 chunks/thread (q=0,1).
  int sR[4][2], sC[4][2], sL[4][2];
#pragma unroll
  for (int s = 0; s < 4; ++s)
#pragma unroll
    for (int qq = 0; qq < 2; ++qq) {
      int reg = (s < 2) ? s : s - 2;
      int ra = reg * 1024 + qq * 512 + wid * 64;  // wave-uniform chunk base in region
      int idx = ra + lane;
      sR[s][qq] = idx >> 3;
      sC[s][qq] = ((idx & 7) ^ ((idx >> 3) & 7)) * 8;
      sL[s][qq] = ((s < 2) ? 0 : 16384) + ra * 8;  // wave-uniform (+lane*16B by HW)
    }

  // prologue: stage k-tile 0 into buf0 (CUR=1 -> dest buf 0), drain, barrier
  STG(0, 1, 0);
  STG(1, 1, 0);
  STG(2, 1, 0);
  STG(3, 1, 0);
  vwait<0>();
  __builtin_amdgcn_s_barrier();

  const int KT = K >> 6;
  for (int kt = 0; kt < KT - 1; ++kt) {
    const int cur = kt & 1;
    const int k1 = (kt + 1) << 6;
    PH(0, 1, cur, 1, 0, k1, -1);  // B-frags + A 0,1 ; stage A-slabs of kt+1
    PH(2, 0, cur, 1, 2, k1, -1);  // A 2,3 ; stage B-slabs of kt+1
    PH(4, 0, cur, 0, 0, 0, -1);   // A 4,5
    PH(6, 0, cur, 0, 0, 0, 0);    // A 6,7 ; drain the 8 prefetch loads (~3 phases old)
  }
  {
    const int cur = (KT - 1) & 1;  // peeled last tile: no staging, nothing outstanding
    PH(0, 1, cur, 0, 0, 0, -1);
    PH(2, 0, cur, 0, 0, 0, -1);
    PH(4, 0, cur, 0, 0, 0, -1);
    PH(6, 0, cur, 0, 0, 0, -1);
  }

#pragma unroll
  for (int i = 0; i < 8; ++i) {
    int m = m0 + wmH * 128 + i * 16 + ((lane >> 4) * 4);
#pragma unroll
    for (int j = 0; j < 4; ++j) {
      int n = n0 + wnq * 64 + j * 16 + l15;
      float bv = (n < 512) ? bias[n] : 0.f;
#pragma unroll
      for (int r = 0; r < 4; ++r) {
        float val = acc[i][j][r] + bv;
        u32 me = (u32)(m + r);
        if (n < 512) {
          fpb[(size_t)me * 512 + n] = f2bf(val);
        } else {
          u32 bdx = me / 196u;
          u32 p = me - bdx * 196u;
          u32 g = (u32)(n - 512) >> 9;
          u32 n9 = (u32)(n - 512) & 511u;
          cnW[(((size_t)bdx * 4 + g) * 196 + p) * 512 + n9] = f2bf(val);
        }
      }
    }
  }
}

// ---------------- hproj: hp[64][2560] = h[64][512] @ wcT[2560][512]^T (f32 out) ----------------
// grid 160 (16-col tiles), 256 thr = 4 waves on K-quarters of 128.
__global__ __launch_bounds__(256) void hproj(const u16* __restrict__ hprev,
                                             const u16* __restrict__ wcT,
                                             float* __restrict__ hp) {
  const int ntile = blockIdx.x;
  const int tid = threadIdx.x, lane = tid & 63, kh = tid >> 6;
  const int l15 = lane & 15;
  const u16* Bp = wcT + (size_t)(ntile * 16 + l15) * 512 + kh * 128 + ((lane >> 4) * 8);
  const u16* Ap = hprev + (size_t)l15 * 512 + kh * 128 + ((lane >> 4) * 8);
  f32x4 acc[4] = {};
#pragma unroll
  for (int ks = 0; ks < 4; ++ks) {
    bf16x8 bb = *(const bf16x8*)(Bp + ks * 32);
#pragma unroll
    for (int mf = 0; mf < 4; ++mf) {
      bf16x8 a = *(const bf16x8*)(Ap + (size_t)mf * 16 * 512 + ks * 32);
      acc[mf] = __builtin_amdgcn_mfma_f32_16x16x32_bf16(a, bb, acc[mf], 0, 0, 0);
    }
  }
  __shared__ float pre[4][64][16];
  const int rrow = (lane >> 4) * 4;
#pragma unroll
  for (int mf = 0; mf < 4; ++mf)
#pragma unroll
    for (int r = 0; r < 4; ++r) pre[kh][mf * 16 + rrow + r][l15] = acc[mf][r];
  __syncthreads();
  const int m = tid >> 2, n = (tid & 3) * 4;
  float4 s;
  float* sp = (float*)&s;
#pragma unroll
  for (int j = 0; j < 4; ++j)
    sp[j] = pre[0][m][n + j] + pre[1][m][n + j] + pre[2][m][n + j] + pre[3][m][n + j];
  *(float4*)(hp + (size_t)m * 2560 + ntile * 16 + n) = s;
}

// ====== attn_gates: e + softmax + (alpha @ cnnW) + cell, one block per (b, n-quarter) ======
// grid 256: b = blk & 63, quarter = blk >> 6 (all 4 quarter-blocks of b share an XCD L2).
__global__ __launch_bounds__(1024) void attn_gates(
    const u16* __restrict__ fpb, const float* __restrict__ hp, const float* __restrict__ v,
    const u16* __restrict__ cw, const float* __restrict__ xw, const float* __restrict__ bi,
    const float* __restrict__ bfg, const float* __restrict__ bc, const float* __restrict__ bo,
    float* __restrict__ cbuf, float* __restrict__ out, u16* __restrict__ hnext, int t) {
  const int b = blockIdx.x & 63;
  const int quarter = blockIdx.x >> 6;  // 128 cols of [0,512)
  const int tid = threadIdx.x;
  const int lane = tid & 63, wid = tid >> 6;
  __shared__ float smem_a[1024];  // [0..511] hwa, [512..1023] vv; later pre4[4][128]
  __shared__ float sm[16];
  __shared__ float alp[200];
  __shared__ float red[8192];  // e[] in [0..255] first, then partials [4][16][16][8]

  float* hwa = smem_a;
  float* vv = smem_a + 512;
  if (tid < 512) {
    hwa[tid] = (t > 0) ? hp[(size_t)b * 2560 + 2048 + tid] : 0.f;
    vv[tid] = v[tid];
  }
  if (tid >= 196 && tid < 256) red[tid] = -3e38f;
  __syncthreads();

  // ---- e[p] = sum_a tanh(fp + hwa) * v ----
  float hw[8], vr[8];
#pragma unroll
  for (int j = 0; j < 8; ++j) {
    hw[j] = hwa[lane * 8 + j];
    vr[j] = vv[lane * 8 + j];
  }
  for (int p = wid; p < NP; p += 16) {
    const u16* fp = fpb + ((size_t)b * NP + p) * 512 + lane * 8;
    uint4 raw = *(const uint4*)fp;
    u32 w[4] = {raw.x, raw.y, raw.z, raw.w};
    float part = 0.f;
#pragma unroll
    for (int j = 0; j < 8; ++j) {
      u16 u = (u16)(w[j >> 1] >> ((j & 1) * 16));
      part += tanh_fast(bf2f(u) + hw[j]) * vr[j];
    }
#pragma unroll
    for (int off = 32; off > 0; off >>= 1) part += __shfl_xor(part, off);
    if (lane == 0) red[p] = part;
  }
  __syncthreads();

  // ---- softmax over 196: wave-level reduce (4 waves hold the 256 padded e-values) ----
  float ev = 0.f, w = 0.f;
  if (tid < 256) {
    ev = red[tid];
    float m_ = ev;
#pragma unroll
    for (int off = 32; off > 0; off >>= 1) m_ = fmaxf(m_, __shfl_xor(m_, off));
    if (lane == 0) sm[wid] = m_;
  }
  __syncthreads();
  if (tid < 256) {
    float mx = fmaxf(fmaxf(sm[0], sm[1]), fmaxf(sm[2], sm[3]));
    w = (tid < NP) ? __builtin_amdgcn_exp2f((ev - mx) * 1.44269504f) : 0.f;
    float s_ = w;
#pragma unroll
    for (int off = 32; off > 0; off >>= 1) s_ += __shfl_xor(s_, off);
    if (lane == 0) sm[8 + wid] = s_;
  }
  __syncthreads();
  if (tid < NP) {
    float tot = (sm[8] + sm[9]) + (sm[10] + sm[11]);
    alp[tid] = w * __builtin_amdgcn_rcpf(tot);
  }
  __syncthreads();

  // ---- gate pre-activation: pre[g][n'] = sum_p alpha[p]*cnnW[b][g][p][quarter*128+n'] ----
  // 1024 thr = g(4) x pg(16) x colc(16), 8 cols each via uint4.
  {
    const int g = tid >> 8, pg = (tid >> 4) & 15, colc = tid & 15;
    const u16* base = cw + ((size_t)(b * 4 + g) * 196) * 512 + quarter * 128 + colc * 8;
    float acc[8] = {};
    for (int i = 0; i < 13; ++i) {
      int p = pg + i * 16;
      if (p < NP) {
        float al = alp[p];
        uint4 raw = *(const uint4*)(base + (size_t)p * 512);
        u32 wds[4] = {raw.x, raw.y, raw.z, raw.w};
#pragma unroll
        for (int j = 0; j < 8; ++j) acc[j] += al * bf2f((u16)(wds[j >> 1] >> ((j & 1) * 16)));
      }
    }
#pragma unroll
    for (int j = 0; j < 8; ++j) red[((g * 16 + pg) * 16 + colc) * 8 + j] = acc[j];
  }
  __syncthreads();

  // reduce over pg into pre4 (aliases smem_a; hw/vr already in regs)
  float* pre4 = smem_a;
  if (tid < 512) {
    const int g = tid >> 7, nn = tid & 127;
    float s = 0.f;
#pragma unroll
    for (int pg = 0; pg < 16; ++pg) s += red[((g * 16 + pg) * 16 + (nn >> 3)) * 8 + (nn & 7)];
    pre4[g * 128 + nn] = s;
  }
  __syncthreads();

  // ---- LSTM cell for this quarter's 128 columns ----
  if (tid < 128) {
    const int ng = quarter * 128 + tid;
    const size_t xwo = ((size_t)t * NB + b) * 2048;
    const size_t hpb = (size_t)b * 2560;
    float hwh0 = 0.f, hwh1 = 0.f, hwh2 = 0.f, hwh3 = 0.f;
    if (t > 0) {
      hwh0 = hp[hpb + ng];
      hwh1 = hp[hpb + 512 + ng];
      hwh2 = hp[hpb + 1024 + ng];
      hwh3 = hp[hpb + 1536 + ng];
    }
    float ip = pre4[0 * 128 + tid] + xw[xwo + ng] + hwh0 + bi[ng];
    float fp = pre4[1 * 128 + tid] + xw[xwo + 512 + ng] + hwh1 + bfg[ng];
    float cp = pre4[2 * 128 + tid] + xw[xwo + 1024 + ng] + hwh2 + bc[ng];
    float op = pre4[3 * 128 + tid] + xw[xwo + 1536 + ng] + hwh3 + bo[ng];
    float it = sigmoid_fast(ip), ft = sigmoid_fast(fp), ot = sigmoid_fast(op);
    float ctl = tanh_fast(cp);
    float cold = (t > 0) ? cbuf[(size_t)b * 512 + ng] : 0.f;
    float cn = ft * cold + it * ctl;
    float hn = ot * tanh_fast(cn);
    cbuf[(size_t)b * 512 + ng] = cn;
    hnext[(size_t)b * 512 + ng] = f2bf(hn);
    out[((size_t)b * NT + t) * 512 + ng] = hn;
    if (t == NT - 1) {
      out[(size_t)NB * NT * 512 + (size_t)b * 512 + ng] = hn;
      out[(size_t)NB * NT * 512 + (size_t)NB * 512 + (size_t)b * 512 + ng] = cn;
    }
  }
}

// ======================= host launcher =======================
extern "C" void kernel_launch(void* const* d_in, const int* in_sizes, int n_in, void* d_out,
                              int out_size, void* d_ws, size_t ws_size, hipStream_t stream) {
  const float* x = (const float*)d_in[0];
  const float* cnn = (const float*)d_in[1];
  const float* Wi = (const float*)d_in[2];
  const float* bi = (const float*)d_in[3];
  const float* Wf = (const float*)d_in[4];
  const float* bfv = (const float*)d_in[5];
  const float* Wc = (const float*)d_in[6];
  const float* bc = (const float*)d_in[7];
  const float* Wo = (const float*)d_in[8];
  const float* bo = (const float*)d_in[9];
  const float* Waf = (const float*)d_in[10];
  const float* Wah = (const float*)d_in[11];
  const float* ba = (const float*)d_in[12];
  const float* v = (const float*)d_in[13];
  float* out = (float*)d_out;

  char* base = (char*)d_ws;
  size_t off = 0;
  auto alloc = [&](size_t bytes) {
    char* r = base + off;
    off += (bytes + 255) & ~(size_t)255;
    return r;
  };
  u16* cnnb = (u16*)alloc((size_t)NB * NP * NE * 2);      // 51.4 MB
  u16* fpb = (u16*)alloc((size_t)NB * NP * NA * 2);       // 12.8 MB
  u16* cnW = (u16*)alloc((size_t)NB * 4 * NP * 512 * 2);  // 51.4 MB [b][g][p][n']
  u16* wbig = (u16*)alloc((size_t)2560 * 2048 * 2);       // 10.5 MB [512 Wa_feat^T | 2048 Wctx^T]
  u16* wcombT = (u16*)alloc((size_t)2560 * 512 * 2);      // 2.6 MB  [2048 hWh | 512 hWa][512]
  u16* wxt = (u16*)alloc((size_t)4 * 512 * 512 * 2);      // 2 MB
  u16* xbT = (u16*)alloc((size_t)NT * NB * 512 * 2);      // 1.3 MB  [t][b][512]
  float* xw = (float*)alloc((size_t)NT * NB * 2048 * 4);  // 10.5 MB [t][b][2048]
  u16* hbuf = (u16*)alloc((size_t)2 * NB * 512 * 2);      // 128 KB (double buffer)
  float* cbuf = (float*)alloc((size_t)NB * 512 * 4);      // 128 KB
  float* hp = (float*)alloc((size_t)NB * 2560 * 4);       // 656 KB [b][hWh 2048 | hWa 512]

  (void)ws_size;
  (void)in_sizes;
  (void)n_in;
  (void)out_size;

  // conversions / transposes
  conv_bf16<<<2048, 256, 0, stream>>>((const float4*)cnn, cnnb, (NB * NP * NE) / 4);
  conv_x<<<dim3(NB, NT), 128, 0, stream>>>(x, xbT);
  {
    dim3 g1(512 / 32, 16, 4);   // wxt: x-part rows 0..511
    transpose_w<<<g1, 256, 0, stream>>>(Wi, Wf, Wc, Wo, wxt, 0, 512);
    dim3 g2(2048 / 32, 16, 1);  // wbig rows 0..511: Wa_feat^T
    transpose_w<<<g2, 256, 0, stream>>>(Waf, Waf, Waf, Waf, wbig, 0, 2048);
    dim3 g3(2048 / 32, 16, 4);  // wbig rows 512..2559: ctx-part of W (rows 1024..3071)
    transpose_w<<<g3, 256, 0, stream>>>(Wi, Wf, Wc, Wo, wbig + (size_t)512 * 2048, 1024, 2048);
    dim3 g4(512 / 32, 16, 4);   // wcombT[0..2047]: h-part rows 512..1023
    transpose_w<<<g4, 256, 0, stream>>>(Wi, Wf, Wc, Wo, wcombT, 512, 512);
    dim3 g5(512 / 32, 16, 1);   // wcombT[2048..2559]: Wa_h
    transpose_w<<<g5, 256, 0, stream>>>(Wah, Wah, Wah, Wah, wcombT + (size_t)2048 * 512, 0, 512);
  }

  // merged: [fpb | cnW] = cnnb @ [Wa_feat^T | Wctx^T]  (M=12544, N=2560, K=2048)
  gemm256<<<49 * 10, 512, 0, stream>>>(cnnb, wbig, ba, fpb, cnW, 2048, 10);

  // xw = xT @ W[:512,:] (4 gates) -> f32 [t*64+b][2048]
  {
    dim3 g(1280 / 128, 2048 / 128);
    gemm_bf16<<<g, 256, 0, stream>>>(xbT, wxt, xw, 1280, 2048, 512);
  }

  // 20-step recurrence: hproj (t>0) + fused attn/gates
  for (int t = 0; t < NT; ++t) {
    const u16* hprev = hbuf + (size_t)(t & 1) * NB * 512;
    u16* hnext = hbuf + (size_t)((t + 1) & 1) * NB * 512;
    if (t > 0) hproj<<<160, 256, 0, stream>>>(hprev, wcombT, hp);
    attn_gates<<<256, 1024, 0, stream>>>(fpb, hp, v, cnW, xw, bi, bfv, bc, bo, cbuf, out, hnext,
                                         t);
  }
}